// Round 1
// baseline (589.220 us; speedup 1.0000x reference)
//
#include <hip/hip_runtime.h>
#include <cstdint>

// FirstEncoder: B=16 S=512 D=1024 H=16 L=128 V=32000, DH=64.
// Faithful points: raw-reshape head split (attention = 256 contiguous [512,64]
// blocks), score scale 1/32 (DH/2), FFN residual f+f=2f.

typedef __bf16 bf16;
typedef __bf16 bf16x8 __attribute__((ext_vector_type(8)));
typedef __bf16 bf16x4 __attribute__((ext_vector_type(4)));
typedef float f32x4 __attribute__((ext_vector_type(4)));

#define MFMA16(a, b, c) __builtin_amdgcn_mfma_f32_16x16x32_bf16((a), (b), (c), 0, 0, 0)

// ---------------------------------------------------------------------------
// Weight transpose + f32->bf16: Wt[n*K + k] = (bf16) W[k*N + n]
// grid (K/64, N/64), 256 threads.
__global__ __launch_bounds__(256) void transpose_kernel(const float* __restrict__ W,
                                                        bf16* __restrict__ Wt,
                                                        int K, int N) {
  __shared__ float tile[64][65];
  const int tk = blockIdx.x * 64, tn = blockIdx.y * 64;
  const int a = threadIdx.x >> 6, b = threadIdx.x & 63;
#pragma unroll
  for (int i = 0; i < 16; ++i) {
    int k = a + i * 4;
    tile[k][b] = W[(size_t)(tk + k) * N + tn + b];
  }
  __syncthreads();
#pragma unroll
  for (int i = 0; i < 16; ++i) {
    int n = a + i * 4;
    Wt[(size_t)(tn + n) * K + tk + b] = (bf16)tile[b][n];
  }
}

// ---------------------------------------------------------------------------
// h0[row, :] = embed[x[row], :] * 32 + posenc(row % 512, :)   (f32 out)
// grid 8192 blocks, 256 threads, 4 cols/thread.
__global__ __launch_bounds__(256) void embed_kernel(const int* __restrict__ x,
                                                    const float* __restrict__ emb,
                                                    float* __restrict__ h0) {
  const int row = blockIdx.x;
  const int s = row & 511;
  const int t = x[row];
  const int c = threadIdx.x * 4;
  const float4 e = *(const float4*)(emb + (size_t)t * 1024 + c);
  const float ev[4] = {e.x, e.y, e.z, e.w};
  float o[4];
#pragma unroll
  for (int j = 0; j < 4; ++j) {
    int cc = c + j;
    float freq = __expf((float)(cc & ~1) * (-9.210340371976184f / 1024.0f));
    float ang = (float)s * freq;
    float pe = (cc & 1) ? cosf(ang) : sinf(ang);
    o[j] = ev[j] * 32.0f + pe;
  }
  float4 r;  r.x = o[0]; r.y = o[1]; r.z = o[2]; r.w = o[3];
  *(float4*)(h0 + (size_t)row * 1024 + c) = r;
}

// ---------------------------------------------------------------------------
// LayerNorm over D=1024. Writes bf16 (GEMM input) and optionally f32.
// In-place (of == in) is safe: each thread reads its 4 elems before writing.
__global__ __launch_bounds__(256) void ln_kernel(const float* __restrict__ in,
                                                 const float* __restrict__ g,
                                                 const float* __restrict__ be,
                                                 bf16* __restrict__ obf,
                                                 float* __restrict__ of) {
  const int row = blockIdx.x;
  const int tid = threadIdx.x;
  const float4 v = ((const float4*)(in + (size_t)row * 1024))[tid];
  float s = v.x + v.y + v.z + v.w;
  float q = v.x * v.x + v.y * v.y + v.z * v.z + v.w * v.w;
#pragma unroll
  for (int off = 32; off > 0; off >>= 1) {
    s += __shfl_down(s, off);
    q += __shfl_down(q, off);
  }
  __shared__ float rs[4], rq[4];
  const int w = tid >> 6, lane = tid & 63;
  if (lane == 0) { rs[w] = s; rq[w] = q; }
  __syncthreads();
  const float S = rs[0] + rs[1] + rs[2] + rs[3];
  const float Qs = rq[0] + rq[1] + rq[2] + rq[3];
  const float mean = S * (1.0f / 1024.0f);
  const float var = Qs * (1.0f / 1024.0f) - mean * mean;
  const float rstd = rsqrtf(var + 1e-5f);
  const float4 gv = ((const float4*)g)[tid];
  const float4 bv = ((const float4*)be)[tid];
  const float y0 = (v.x - mean) * rstd * gv.x + bv.x;
  const float y1 = (v.y - mean) * rstd * gv.y + bv.y;
  const float y2 = (v.z - mean) * rstd * gv.z + bv.z;
  const float y3 = (v.w - mean) * rstd * gv.w + bv.w;
  bf16x4 ob = {(bf16)y0, (bf16)y1, (bf16)y2, (bf16)y3};
  ((bf16x4*)(obf + (size_t)row * 1024))[tid] = ob;
  if (of) {
    float4 o4;  o4.x = y0; o4.y = y1; o4.z = y2; o4.w = y3;
    ((float4*)(of + (size_t)row * 1024))[tid] = o4;
  }
}

// ---------------------------------------------------------------------------
// GEMM: C[M,N] = A[M,K](bf16) @ Bt[N,K]^T(bf16) + bias, with epilogue MODE:
//  0: out bf16 = acc+bias              (Q/K/V)
//  1: out f32  = acc+bias+resid        (Wo, in-place residual OK)
//  2: out bf16 = leaky_relu(acc+bias)  (W1)
//  3: out f32  = 2*(acc+bias)          (W2, f+f)
//  5: out f32  = acc + bias2(col)      (mu|sig concat: bias for col<128, resid
//                                       param reused as bsig for col>=128)
// 128x128 tile, BK=32, 256 threads (4 waves), wave -> 64x64 (4x4 mfma tiles).
template <int MODE>
__global__ __launch_bounds__(256) void gemm_kernel(const bf16* __restrict__ A,
                                                   const bf16* __restrict__ Bt,
                                                   const float* __restrict__ bias,
                                                   void* __restrict__ outv,
                                                   const float* __restrict__ resid,
                                                   int M, int N, int K) {
  __shared__ __attribute__((aligned(16))) bf16 Asm[128 * 32];
  __shared__ __attribute__((aligned(16))) bf16 Bsm[128 * 32];
  const int tid = threadIdx.x;
  const int wv = tid >> 6, lane = tid & 63;
  const int quad = lane >> 4, l15 = lane & 15;
  const int m0 = blockIdx.x * 128, n0 = blockIdx.y * 128;
  const int wm = wv & 1, wn = wv >> 1;

  f32x4 acc[4][4];
#pragma unroll
  for (int i = 0; i < 4; ++i)
#pragma unroll
    for (int j = 0; j < 4; ++j) acc[i][j] = {0.f, 0.f, 0.f, 0.f};

  // staging: 512 chunks of 8 bf16 (16B); thread handles chunks tid and tid+256
  const int r0 = tid >> 2, k0c = (tid & 3) * 8;          // rows 0..63
  const int r1 = (tid + 256) >> 2, k1c = ((tid + 256) & 3) * 8;  // rows 64..127
  const bf16* Ag0 = A + (size_t)(m0 + r0) * K + k0c;
  const bf16* Ag1 = A + (size_t)(m0 + r1) * K + k1c;
  const bf16* Bg0 = Bt + (size_t)(n0 + r0) * K + k0c;
  const bf16* Bg1 = Bt + (size_t)(n0 + r1) * K + k1c;

  for (int k0 = 0; k0 < K; k0 += 32) {
    const uint4 a0 = *(const uint4*)(Ag0 + k0);
    const uint4 a1 = *(const uint4*)(Ag1 + k0);
    const uint4 b0 = *(const uint4*)(Bg0 + k0);
    const uint4 b1 = *(const uint4*)(Bg1 + k0);
    __syncthreads();  // previous iteration's LDS reads done
    *(uint4*)(&Asm[r0 * 32 + k0c]) = a0;
    *(uint4*)(&Asm[r1 * 32 + k1c]) = a1;
    *(uint4*)(&Bsm[r0 * 32 + k0c]) = b0;
    *(uint4*)(&Bsm[r1 * 32 + k1c]) = b1;
    __syncthreads();
    bf16x8 af[4], bfr[4];
#pragma unroll
    for (int mi = 0; mi < 4; ++mi)
      af[mi] = *(const bf16x8*)(&Asm[(wm * 64 + mi * 16 + l15) * 32 + quad * 8]);
#pragma unroll
    for (int ni = 0; ni < 4; ++ni)
      bfr[ni] = *(const bf16x8*)(&Bsm[(wn * 64 + ni * 16 + l15) * 32 + quad * 8]);
#pragma unroll
    for (int mi = 0; mi < 4; ++mi)
#pragma unroll
      for (int ni = 0; ni < 4; ++ni)
        acc[mi][ni] = MFMA16(af[mi], bfr[ni], acc[mi][ni]);
  }

  float* outf = (float*)outv;
  bf16* outb = (bf16*)outv;
#pragma unroll
  for (int ni = 0; ni < 4; ++ni) {
    const int col = n0 + wn * 64 + ni * 16 + l15;
    float bv;
    if constexpr (MODE == 5)
      bv = (col < 128) ? bias[col] : resid[col - 128];
    else
      bv = bias[col];
#pragma unroll
    for (int mi = 0; mi < 4; ++mi) {
#pragma unroll
      for (int r = 0; r < 4; ++r) {
        const int row = m0 + wm * 64 + mi * 16 + quad * 4 + r;
        const size_t idx = (size_t)row * N + col;
        float v = acc[mi][ni][r] + bv;
        if constexpr (MODE == 0) outb[idx] = (bf16)v;
        else if constexpr (MODE == 1) outf[idx] = v + resid[idx];
        else if constexpr (MODE == 2) outb[idx] = (bf16)(v > 0.f ? v : 0.01f * v);
        else if constexpr (MODE == 3) outf[idx] = 2.0f * v;
        else outf[idx] = v;  // MODE 5
      }
    }
  }
}

// ---------------------------------------------------------------------------
// Attention: 256 blocks (one per b*h), 256 threads (4 waves).
// Q/K/V are the flat [8192,1024] buffers: block bh owns rows [bh*512*64, ...).
// K in LDS (row pad 72), V^T in LDS (row pad 520), online softmax, scale 1/32.
__global__ __launch_bounds__(256) void attn_kernel(const bf16* __restrict__ Qg,
                                                   const bf16* __restrict__ Kg,
                                                   const bf16* __restrict__ Vg,
                                                   bf16* __restrict__ ctx) {
  __shared__ __attribute__((aligned(16))) bf16 Ksm[512 * 72];   // 72 KB
  __shared__ __attribute__((aligned(16))) bf16 Vt[64 * 520];    // 66.56 KB
  __shared__ __attribute__((aligned(16))) bf16 Pscr[4][512];    // 4 KB
  const int tid = threadIdx.x;
  const size_t base = (size_t)blockIdx.x * (512 * 64);

  // stage K: 512x64 -> Ksm stride 72 (16B vector copies)
#pragma unroll
  for (int i = 0; i < 16; ++i) {
    int chunk = i * 256 + tid;           // 4096 chunks of 8 bf16
    int r = chunk >> 3, c = (chunk & 7) * 8;
    uint4 v = *(const uint4*)(Kg + base + (size_t)r * 64 + c);
    *(uint4*)(&Ksm[r * 72 + c]) = v;
  }
  // stage V transposed: Vt[d][kv], stride 520
  for (int i = 0; i < 64; ++i) {
    int idx = (i * 256 + tid) * 2;       // even element index in [512*64]
    int kv = idx >> 6, d = idx & 63;
    unsigned int v = *(const unsigned int*)(Vg + base + (size_t)kv * 64 + d);
    Vt[(size_t)d * 520 + kv] = ((const bf16*)&v)[0];
    Vt[(size_t)(d + 1) * 520 + kv] = ((const bf16*)&v)[1];
  }
  __syncthreads();

  const int w = tid >> 6, lane = tid & 63;
  const int quad = lane >> 4, l15 = lane & 15;
  bf16* ps = &Pscr[w][0];
  const f32x4 fz = {0.f, 0.f, 0.f, 0.f};

  for (int qt = 0; qt < 8; ++qt) {
    const int q0 = w * 128 + qt * 16;
    const bf16x8 a0 = *(const bf16x8*)(Qg + base + (size_t)(q0 + l15) * 64 + quad * 8);
    const bf16x8 a1 = *(const bf16x8*)(Qg + base + (size_t)(q0 + l15) * 64 + 32 + quad * 8);
    float m_i[4] = {-1e30f, -1e30f, -1e30f, -1e30f};
    float l_i[4] = {0.f, 0.f, 0.f, 0.f};
    f32x4 o[4];
#pragma unroll
    for (int ni = 0; ni < 4; ++ni) o[ni] = fz;

    for (int nb = 0; nb < 16; ++nb) {
      const int n0 = nb * 32;
      const bf16x8 b00 = *(const bf16x8*)(&Ksm[(n0 + l15) * 72 + quad * 8]);
      const bf16x8 b01 = *(const bf16x8*)(&Ksm[(n0 + l15) * 72 + 32 + quad * 8]);
      const bf16x8 b10 = *(const bf16x8*)(&Ksm[(n0 + 16 + l15) * 72 + quad * 8]);
      const bf16x8 b11 = *(const bf16x8*)(&Ksm[(n0 + 16 + l15) * 72 + 32 + quad * 8]);
      f32x4 s0 = MFMA16(a0, b00, fz);
      s0 = MFMA16(a1, b01, s0);
      f32x4 s1 = MFMA16(a0, b10, fz);
      s1 = MFMA16(a1, b11, s1);
      float alpha[4];
#pragma unroll
      for (int r = 0; r < 4; ++r) {
        const float x0 = s0[r] * 0.03125f;     // scale = 1/(DH/2) = 1/32
        const float x1 = s1[r] * 0.03125f;
        float mr = fmaxf(x0, x1);
        mr = fmaxf(mr, __shfl_xor(mr, 1));
        mr = fmaxf(mr, __shfl_xor(mr, 2));
        mr = fmaxf(mr, __shfl_xor(mr, 4));
        mr = fmaxf(mr, __shfl_xor(mr, 8));
        const float mn = fmaxf(m_i[r], mr);
        alpha[r] = __expf(m_i[r] - mn);
        m_i[r] = mn;
        const float p0 = __expf(x0 - mn), p1 = __expf(x1 - mn);
        float rsum = p0 + p1;
        rsum += __shfl_xor(rsum, 1);
        rsum += __shfl_xor(rsum, 2);
        rsum += __shfl_xor(rsum, 4);
        rsum += __shfl_xor(rsum, 8);
        l_i[r] = l_i[r] * alpha[r] + rsum;
        // P tile (C layout) -> per-wave LDS scratch [16 x 32]
        ps[(quad * 4 + r) * 32 + l15] = (bf16)p0;
        ps[(quad * 4 + r) * 32 + 16 + l15] = (bf16)p1;
      }
#pragma unroll
      for (int ni = 0; ni < 4; ++ni) {
        o[ni][0] *= alpha[0];
        o[ni][1] *= alpha[1];
        o[ni][2] *= alpha[2];
        o[ni][3] *= alpha[3];
      }
      // re-read P in A-operand layout, then PV mfma (K=32 kv rows)
      const bf16x8 pf = *(const bf16x8*)(ps + l15 * 32 + quad * 8);
#pragma unroll
      for (int ni = 0; ni < 4; ++ni) {
        const bf16x8 vf = *(const bf16x8*)(&Vt[(size_t)(ni * 16 + l15) * 520 + n0 + quad * 8]);
        o[ni] = MFMA16(pf, vf, o[ni]);
      }
    }
    float inv_l[4];
#pragma unroll
    for (int r = 0; r < 4; ++r) inv_l[r] = 1.0f / l_i[r];
#pragma unroll
    for (int ni = 0; ni < 4; ++ni) {
#pragma unroll
      for (int r = 0; r < 4; ++r) {
        const float v = o[ni][r] * inv_l[r];
        ctx[base + (size_t)(q0 + quad * 4 + r) * 64 + ni * 16 + l15] = (bf16)v;
      }
    }
  }
}

// ---------------------------------------------------------------------------
// z = mu + exp(sig_raw) * eps, reading the fused [8192, 256] mu|sig buffer.
__global__ __launch_bounds__(256) void final_kernel(const float* __restrict__ musg,
                                                    const float* __restrict__ eps,
                                                    float* __restrict__ z) {
  const int i = blockIdx.x * 256 + threadIdx.x;  // 0..262143 (float4 units)
  const int row = i >> 5;
  const int c = (i & 31) * 4;
  const float4 m = *(const float4*)(musg + (size_t)row * 256 + c);
  const float4 s = *(const float4*)(musg + (size_t)row * 256 + 128 + c);
  const float4 e = *(const float4*)(eps + (size_t)row * 128 + c);
  float4 r;
  r.x = m.x + __expf(s.x) * e.x;
  r.y = m.y + __expf(s.y) * e.y;
  r.z = m.z + __expf(s.z) * e.z;
  r.w = m.w + __expf(s.w) * e.w;
  *(float4*)(z + (size_t)row * 128 + c) = r;
}

// ---------------------------------------------------------------------------
extern "C" void kernel_launch(void* const* d_in, const int* in_sizes, int n_in,
                              void* d_out, int out_size, void* d_ws, size_t ws_size,
                              hipStream_t stream) {
  (void)in_sizes; (void)n_in; (void)out_size; (void)ws_size;
  const int* x = (const int*)d_in[0];
  const float* emb = (const float*)d_in[1];
  const float* Wq = (const float*)d_in[2];
  const float* bq = (const float*)d_in[3];
  const float* Wk = (const float*)d_in[4];
  const float* bkb = (const float*)d_in[5];
  const float* Wv = (const float*)d_in[6];
  const float* bv = (const float*)d_in[7];
  const float* Wo = (const float*)d_in[8];
  const float* bo = (const float*)d_in[9];
  const float* g1 = (const float*)d_in[10];
  const float* be1 = (const float*)d_in[11];
  const float* W1 = (const float*)d_in[12];
  const float* bf1 = (const float*)d_in[13];
  const float* W2 = (const float*)d_in[14];
  const float* bf2 = (const float*)d_in[15];
  const float* g2 = (const float*)d_in[16];
  const float* be2 = (const float*)d_in[17];
  const float* g3 = (const float*)d_in[18];
  const float* be3 = (const float*)d_in[19];
  const float* Wmu = (const float*)d_in[20];
  const float* bmu = (const float*)d_in[21];
  const float* Wsig = (const float*)d_in[22];
  const float* bsig = (const float*)d_in[23];
  const float* eps = (const float*)d_in[24];
  float* z = (float*)d_out;

  const int M = 8192, D = 1024;
  char* ws = (char*)d_ws;
  size_t off = 0;
  auto alloc = [&](size_t b) {
    char* p = ws + off;
    off += (b + 255) & ~(size_t)255;
    return p;
  };
  bf16* wqT = (bf16*)alloc((size_t)1024 * 1024 * 2);
  bf16* wkT = (bf16*)alloc((size_t)1024 * 1024 * 2);
  bf16* wvT = (bf16*)alloc((size_t)1024 * 1024 * 2);
  bf16* woT = (bf16*)alloc((size_t)1024 * 1024 * 2);
  bf16* w1T = (bf16*)alloc((size_t)1024 * 1024 * 2);
  bf16* w2T = (bf16*)alloc((size_t)1024 * 1024 * 2);
  bf16* wmsT = (bf16*)alloc((size_t)256 * 1024 * 2);   // [Wmu^T ; Wsig^T]
  float* hA = (float*)alloc((size_t)M * D * 4);        // h0 -> h1_f32 -> h2 -> h4
  bf16* hb = (bf16*)alloc((size_t)M * D * 2);          // h1 -> h3 -> h5 (bf16)
  bf16* Qb = (bf16*)alloc((size_t)M * D * 2);          // Q -> ffn hidden
  bf16* Kb = (bf16*)alloc((size_t)M * D * 2);
  bf16* Vb = (bf16*)alloc((size_t)M * D * 2);
  bf16* Cb = (bf16*)alloc((size_t)M * D * 2);          // ctx -> mu|sig (f32)
  float* musg = (float*)Cb;                            // [8192, 256] f32 = 8 MB

  dim3 b256(256);
  // weights -> bf16 transposed [N,K]
  transpose_kernel<<<dim3(16, 16), b256, 0, stream>>>(Wq, wqT, 1024, 1024);
  transpose_kernel<<<dim3(16, 16), b256, 0, stream>>>(Wk, wkT, 1024, 1024);
  transpose_kernel<<<dim3(16, 16), b256, 0, stream>>>(Wv, wvT, 1024, 1024);
  transpose_kernel<<<dim3(16, 16), b256, 0, stream>>>(Wo, woT, 1024, 1024);
  transpose_kernel<<<dim3(16, 16), b256, 0, stream>>>(W1, w1T, 1024, 1024);
  transpose_kernel<<<dim3(16, 16), b256, 0, stream>>>(W2, w2T, 1024, 1024);
  transpose_kernel<<<dim3(16, 2), b256, 0, stream>>>(Wmu, wmsT, 1024, 128);
  transpose_kernel<<<dim3(16, 2), b256, 0, stream>>>(Wsig, wmsT + (size_t)128 * 1024, 1024, 128);

  embed_kernel<<<8192, b256, 0, stream>>>(x, emb, hA);
  ln_kernel<<<8192, b256, 0, stream>>>(hA, g1, be1, hb, hA);  // h1 (bf16 + f32)

  gemm_kernel<0><<<dim3(64, 8), b256, 0, stream>>>(hb, wqT, bq, Qb, nullptr, M, D, D);
  gemm_kernel<0><<<dim3(64, 8), b256, 0, stream>>>(hb, wkT, bkb, Kb, nullptr, M, D, D);
  gemm_kernel<0><<<dim3(64, 8), b256, 0, stream>>>(hb, wvT, bv, Vb, nullptr, M, D, D);

  attn_kernel<<<256, b256, 0, stream>>>(Qb, Kb, Vb, Cb);

  gemm_kernel<1><<<dim3(64, 8), b256, 0, stream>>>(Cb, woT, bo, hA, hA, M, D, D);  // h2 = h1 + ctx@Wo
  ln_kernel<<<8192, b256, 0, stream>>>(hA, g2, be2, hb, nullptr);                  // h3
  gemm_kernel<2><<<dim3(64, 8), b256, 0, stream>>>(hb, w1T, bf1, Qb, nullptr, M, D, D);  // leaky
  gemm_kernel<3><<<dim3(64, 8), b256, 0, stream>>>(Qb, w2T, bf2, hA, nullptr, M, D, D);  // h4 = 2f
  ln_kernel<<<8192, b256, 0, stream>>>(hA, g3, be3, hb, nullptr);                  // h5
  gemm_kernel<5><<<dim3(64, 2), b256, 0, stream>>>(hb, wmsT, bmu, musg, bsig, M, 256, D);
  final_kernel<<<1024, b256, 0, stream>>>(musg, eps, z);
}

// Round 2
// 506.860 us; speedup vs baseline: 1.1625x; 1.1625x over previous
//
#include <hip/hip_runtime.h>
#include <cstdint>

// FirstEncoder: B=16 S=512 D=1024 H=16 L=128 V=32000, DH=64.
// Faithful: raw-reshape head split (head (b,h) = contiguous [512,64] block of
// the flat [8192,1024] buffer), score scale 1/32 (DH/2), FFN residual f+f=2f.

typedef __bf16 bf16;
typedef __bf16 bf16x8 __attribute__((ext_vector_type(8)));
typedef __bf16 bf16x4 __attribute__((ext_vector_type(4)));
typedef float f32x4 __attribute__((ext_vector_type(4)));

#define MFMA16(a, b, c) __builtin_amdgcn_mfma_f32_16x16x32_bf16((a), (b), (c), 0, 0, 0)

#if __has_builtin(__builtin_amdgcn_exp2f)
#define EXP2F(x) __builtin_amdgcn_exp2f(x)
#else
#define EXP2F(x) exp2f(x)
#endif

// async 16B global->LDS (lane i lands at wave-uniform base + i*16)
__device__ __forceinline__ void async16(const bf16* g, bf16* l) {
  __builtin_amdgcn_global_load_lds(
      (const __attribute__((address_space(1))) unsigned int*)g,
      (__attribute__((address_space(3))) unsigned int*)l, 16, 0, 0);
}

// ---------------------------------------------------------------------------
// 6x fused weight transpose + f32->bf16 (all 1024x1024): Wt[n*1024+k]=W[k*1024+n]
struct TP6 {
  const float* src[6];
  bf16* dst[6];
};
__global__ __launch_bounds__(256) void transpose6_kernel(TP6 p) {
  const float* __restrict__ W = p.src[blockIdx.z];
  bf16* __restrict__ Wt = p.dst[blockIdx.z];
  __shared__ float tile[64][65];
  const int tk = blockIdx.x * 64, tn = blockIdx.y * 64;
  const int a = threadIdx.x >> 6, b = threadIdx.x & 63;
#pragma unroll
  for (int i = 0; i < 16; ++i) {
    int k = a + i * 4;
    tile[k][b] = W[(size_t)(tk + k) * 1024 + tn + b];
  }
  __syncthreads();
#pragma unroll
  for (int i = 0; i < 16; ++i) {
    int n = a + i * 4;
    Wt[(size_t)(tn + n) * 1024 + tk + b] = (bf16)tile[b][n];
  }
}

// generic (for Wmu/Wsig, K=1024 N=128)
__global__ __launch_bounds__(256) void transpose_kernel(const float* __restrict__ W,
                                                        bf16* __restrict__ Wt,
                                                        int K, int N) {
  __shared__ float tile[64][65];
  const int tk = blockIdx.x * 64, tn = blockIdx.y * 64;
  const int a = threadIdx.x >> 6, b = threadIdx.x & 63;
#pragma unroll
  for (int i = 0; i < 16; ++i) {
    int k = a + i * 4;
    tile[k][b] = W[(size_t)(tk + k) * N + tn + b];
  }
  __syncthreads();
#pragma unroll
  for (int i = 0; i < 16; ++i) {
    int n = a + i * 4;
    Wt[(size_t)(tn + n) * K + tk + b] = (bf16)tile[b][n];
  }
}

// ---------------------------------------------------------------------------
// Fused embed (*32 + posenc) + LayerNorm1. Writes bf16 + f32.
__global__ __launch_bounds__(256) void embed_ln_kernel(const int* __restrict__ x,
                                                       const float* __restrict__ emb,
                                                       const float* __restrict__ g,
                                                       const float* __restrict__ be,
                                                       bf16* __restrict__ obf,
                                                       float* __restrict__ of) {
  const int row = blockIdx.x;
  const int s = row & 511;
  const int t = x[row];
  const int tid = threadIdx.x;
  const int c = tid * 4;
  const float4 e = *(const float4*)(emb + (size_t)t * 1024 + c);
  const float ev[4] = {e.x, e.y, e.z, e.w};
  float o[4];
#pragma unroll
  for (int j = 0; j < 4; ++j) {
    int cc = c + j;
    float freq = __expf((float)(cc & ~1) * (-9.210340371976184f / 1024.0f));
    float ang = (float)s * freq;
    float pe = (cc & 1) ? cosf(ang) : sinf(ang);
    o[j] = ev[j] * 32.0f + pe;
  }
  float sm = o[0] + o[1] + o[2] + o[3];
  float q = o[0] * o[0] + o[1] * o[1] + o[2] * o[2] + o[3] * o[3];
#pragma unroll
  for (int off = 32; off > 0; off >>= 1) {
    sm += __shfl_down(sm, off);
    q += __shfl_down(q, off);
  }
  __shared__ float rs[4], rq[4];
  const int w = tid >> 6, lane = tid & 63;
  if (lane == 0) { rs[w] = sm; rq[w] = q; }
  __syncthreads();
  const float S = rs[0] + rs[1] + rs[2] + rs[3];
  const float Qs = rq[0] + rq[1] + rq[2] + rq[3];
  const float mean = S * (1.0f / 1024.0f);
  const float var = Qs * (1.0f / 1024.0f) - mean * mean;
  const float rstd = rsqrtf(var + 1e-5f);
  const float4 gv = ((const float4*)g)[tid];
  const float4 bv = ((const float4*)be)[tid];
  const float gvv[4] = {gv.x, gv.y, gv.z, gv.w};
  const float bvv[4] = {bv.x, bv.y, bv.z, bv.w};
  float y[4];
#pragma unroll
  for (int j = 0; j < 4; ++j) y[j] = (o[j] - mean) * rstd * gvv[j] + bvv[j];
  bf16x4 ob = {(bf16)y[0], (bf16)y[1], (bf16)y[2], (bf16)y[3]};
  ((bf16x4*)(obf + (size_t)row * 1024))[tid] = ob;
  float4 o4;  o4.x = y[0]; o4.y = y[1]; o4.z = y[2]; o4.w = y[3];
  ((float4*)(of + (size_t)row * 1024))[tid] = o4;
}

// ---------------------------------------------------------------------------
// LayerNorm over D=1024, f32 in -> bf16 out (and optional f32).
__global__ __launch_bounds__(256) void ln_kernel(const float* __restrict__ in,
                                                 const float* __restrict__ g,
                                                 const float* __restrict__ be,
                                                 bf16* __restrict__ obf,
                                                 float* __restrict__ of) {
  const int row = blockIdx.x;
  const int tid = threadIdx.x;
  const float4 v = ((const float4*)(in + (size_t)row * 1024))[tid];
  float s = v.x + v.y + v.z + v.w;
  float q = v.x * v.x + v.y * v.y + v.z * v.z + v.w * v.w;
#pragma unroll
  for (int off = 32; off > 0; off >>= 1) {
    s += __shfl_down(s, off);
    q += __shfl_down(q, off);
  }
  __shared__ float rs[4], rq[4];
  const int w = tid >> 6, lane = tid & 63;
  if (lane == 0) { rs[w] = s; rq[w] = q; }
  __syncthreads();
  const float S = rs[0] + rs[1] + rs[2] + rs[3];
  const float Qs = rq[0] + rq[1] + rq[2] + rq[3];
  const float mean = S * (1.0f / 1024.0f);
  const float var = Qs * (1.0f / 1024.0f) - mean * mean;
  const float rstd = rsqrtf(var + 1e-5f);
  const float4 gv = ((const float4*)g)[tid];
  const float4 bv = ((const float4*)be)[tid];
  const float y0 = (v.x - mean) * rstd * gv.x + bv.x;
  const float y1 = (v.y - mean) * rstd * gv.y + bv.y;
  const float y2 = (v.z - mean) * rstd * gv.z + bv.z;
  const float y3 = (v.w - mean) * rstd * gv.w + bv.w;
  bf16x4 ob = {(bf16)y0, (bf16)y1, (bf16)y2, (bf16)y3};
  ((bf16x4*)(obf + (size_t)row * 1024))[tid] = ob;
  if (of) {
    float4 o4;  o4.x = y0; o4.y = y1; o4.z = y2; o4.w = y3;
    ((float4*)(of + (size_t)row * 1024))[tid] = o4;
  }
}

// ---------------------------------------------------------------------------
// GEMM: C[M,N] = A[M,K](bf16) @ Bt[N,K]^T(bf16) + bias. m97 structure:
// global_load_lds width-16 staging + XOR-swizzled LDS chunks (2-way max).
// MODE: 0 bf16 out; 1 f32 out + resid; 2 bf16 leaky; 3 f32 2*(..); 5 mu|sig.
template <int MODE>
__global__ __launch_bounds__(256) void gemm_kernel(const bf16* __restrict__ A,
                                                   const bf16* __restrict__ Bt,
                                                   const float* __restrict__ bias,
                                                   void* __restrict__ outv,
                                                   const float* __restrict__ resid,
                                                   int M, int N, int K) {
  __shared__ __attribute__((aligned(16))) bf16 Asm[128 * 32];
  __shared__ __attribute__((aligned(16))) bf16 Bsm[128 * 32];
  const int tid = threadIdx.x;
  const int wv = tid >> 6, lane = tid & 63;
  const int quad = lane >> 4, l15 = lane & 15;
  const int m0 = blockIdx.x * 128, n0 = blockIdx.y * 128;
  const int wm = wv & 1, wn = wv >> 1;

  f32x4 acc[4][4];
#pragma unroll
  for (int i = 0; i < 4; ++i)
#pragma unroll
    for (int j = 0; j < 4; ++j) acc[i][j] = {0.f, 0.f, 0.f, 0.f};

  // chunk s (16B) lives at LDS slot s; global chunk col = (s&3) ^ ((row>>1)&3)
  const int r0 = tid >> 2, c0 = ((tid & 3) ^ ((r0 >> 1) & 3)) * 8;
  const int r1 = (tid + 256) >> 2, c1 = ((tid & 3) ^ ((r1 >> 1) & 3)) * 8;
  const bf16* Ag0 = A + (size_t)(m0 + r0) * K + c0;
  const bf16* Ag1 = A + (size_t)(m0 + r1) * K + c1;
  const bf16* Bg0 = Bt + (size_t)(n0 + r0) * K + c0;
  const bf16* Bg1 = Bt + (size_t)(n0 + r1) * K + c1;
  bf16* lA0 = &Asm[tid * 8];
  bf16* lA1 = &Asm[(tid + 256) * 8];
  bf16* lB0 = &Bsm[tid * 8];
  bf16* lB1 = &Bsm[(tid + 256) * 8];

  for (int k0 = 0; k0 < K; k0 += 32) {
    async16(Ag0 + k0, lA0);
    async16(Ag1 + k0, lA1);
    async16(Bg0 + k0, lB0);
    async16(Bg1 + k0, lB1);
    __syncthreads();
    bf16x8 af[4], bfr[4];
#pragma unroll
    for (int mi = 0; mi < 4; ++mi) {
      const int row = wm * 64 + mi * 16 + l15;
      af[mi] = *(const bf16x8*)(&Asm[(row * 4 + (quad ^ ((row >> 1) & 3))) * 8]);
    }
#pragma unroll
    for (int ni = 0; ni < 4; ++ni) {
      const int row = wn * 64 + ni * 16 + l15;
      bfr[ni] = *(const bf16x8*)(&Bsm[(row * 4 + (quad ^ ((row >> 1) & 3))) * 8]);
    }
#pragma unroll
    for (int mi = 0; mi < 4; ++mi)
#pragma unroll
      for (int ni = 0; ni < 4; ++ni)
        acc[mi][ni] = MFMA16(af[mi], bfr[ni], acc[mi][ni]);
    __syncthreads();
  }

  float* outf = (float*)outv;
  bf16* outb = (bf16*)outv;
#pragma unroll
  for (int ni = 0; ni < 4; ++ni) {
    const int col = n0 + wn * 64 + ni * 16 + l15;
    float bv;
    if constexpr (MODE == 5)
      bv = (col < 128) ? bias[col] : resid[col - 128];
    else
      bv = bias[col];
#pragma unroll
    for (int mi = 0; mi < 4; ++mi) {
#pragma unroll
      for (int r = 0; r < 4; ++r) {
        const int row = m0 + wm * 64 + mi * 16 + quad * 4 + r;
        const size_t idx = (size_t)row * N + col;
        float v = acc[mi][ni][r] + bv;
        if constexpr (MODE == 0) outb[idx] = (bf16)v;
        else if constexpr (MODE == 1) outf[idx] = v + resid[idx];
        else if constexpr (MODE == 2) outb[idx] = (bf16)(v > 0.f ? v : 0.01f * v);
        else if constexpr (MODE == 3) outf[idx] = 2.0f * v;
        else outf[idx] = v;  // MODE 5
      }
    }
  }
}

// ---------------------------------------------------------------------------
// V transpose per head: Vb flat [256 bh][512 kv][64 d] -> VtG [256 bh][64 d][512 kv]
// grid (256, 8), 256 threads; f32 LDS tile (stride 65 dwords -> 2-way max).
__global__ __launch_bounds__(256) void vtrans_kernel(const bf16* __restrict__ Vb,
                                                     bf16* __restrict__ VtG) {
  __shared__ float t[64][65];
  const int bh = blockIdx.x, kt = blockIdx.y;
  const int tid = threadIdx.x;
  const bf16* src = Vb + (size_t)bh * 32768 + (size_t)kt * 4096;
#pragma unroll
  for (int i = 0; i < 2; ++i) {
    int s = i * 256 + tid;               // kv row = s>>3, col c = (s&7)*8
    int r = s >> 3, c = (s & 7) * 8;
    bf16x8 v = *(const bf16x8*)(src + (size_t)s * 8);
#pragma unroll
    for (int j = 0; j < 8; ++j) t[r][c + j] = (float)v[j];
  }
  __syncthreads();
  bf16* dst = VtG + (size_t)bh * 32768 + kt * 64;
#pragma unroll
  for (int i = 0; i < 2; ++i) {
    int s = i * 256 + tid;
    int d = s >> 3, kc = (s & 7) * 8;
    bf16 tmp[8];
#pragma unroll
    for (int j = 0; j < 8; ++j) tmp[j] = (bf16)t[kc + j][d];
    *(uint4*)(dst + (size_t)d * 512 + kc) = *(const uint4*)tmp;
  }
}

// ---------------------------------------------------------------------------
// Flash-style attention. grid (256 bh, 4 qblk), 256 threads (4 waves).
// Wave owns 32 q rows. kv chunks of 128 staged via global_load_lds with XOR
// swizzle. No-max softmax (scores/32 have |x| < ~1): p = exp2(score*log2e/32),
// Q pre-scaled by log2e/32. l accumulated per-lane, reduced once at end.
__global__ __launch_bounds__(256) void attn_kernel(const bf16* __restrict__ Qg,
                                                   const bf16* __restrict__ Kg,
                                                   const bf16* __restrict__ Vt,
                                                   bf16* __restrict__ ctx) {
  __shared__ __attribute__((aligned(16))) bf16 Ksm[128 * 64];   // 16 KB
  __shared__ __attribute__((aligned(16))) bf16 Vsm[64 * 128];   // 16 KB
  __shared__ __attribute__((aligned(16))) bf16 Psm[4][16 * 128];// 16 KB
  const int tid = threadIdx.x;
  const int w = tid >> 6, lane = tid & 63;
  const int quad = lane >> 4, l15 = lane & 15;
  const int bh = blockIdx.x;
  const size_t base = (size_t)bh * 32768;
  const bf16* Vth = Vt + base;
  const int qbase = blockIdx.y * 128 + w * 32;
  const f32x4 fz = {0.f, 0.f, 0.f, 0.f};

  // Q a-frags, pre-scaled by log2(e)/32
  bf16x8 a[2][2];
#pragma unroll
  for (int qt = 0; qt < 2; ++qt)
#pragma unroll
    for (int hf = 0; hf < 2; ++hf) {
      bf16x8 tq = *(const bf16x8*)(Qg + base +
                   (size_t)(qbase + qt * 16 + l15) * 64 + hf * 32 + quad * 8);
#pragma unroll
      for (int e = 0; e < 8; ++e) tq[e] = (bf16)((float)tq[e] * 0.045111758f);
      a[qt][hf] = tq;
    }

  f32x4 o[2][4];
  float l_i[2][4];
#pragma unroll
  for (int qt = 0; qt < 2; ++qt)
#pragma unroll
    for (int i = 0; i < 4; ++i) { o[qt][i] = fz; l_i[qt][i] = 0.f; }

  for (int kv0 = 0; kv0 < 512; kv0 += 128) {
    // stage K[128][64]: chunk slot s: row=s>>3, col chunk = (s&7)^(row&7)
#pragma unroll
    for (int i = 0; i < 4; ++i) {
      int s = i * 256 + tid;
      int r = s >> 3, c = (s & 7) ^ (r & 7);
      async16(Kg + base + (size_t)(kv0 + r) * 64 + c * 8, &Ksm[s * 8]);
    }
    // stage Vt[64][128]: slot s: d=s>>4, cs=s&15, c=(cs&8)|((cs&7)^(d&7))
#pragma unroll
    for (int i = 0; i < 4; ++i) {
      int s = i * 256 + tid;
      int d = s >> 4, cs = s & 15;
      int c = (cs & 8) | ((cs & 7) ^ (d & 7));
      async16(Vth + (size_t)d * 512 + kv0 + c * 8, &Vsm[s * 8]);
    }
    __syncthreads();

    // QK^T: S[2 qt][8 kv-tiles], sharing K frags across qt
    f32x4 sc[2][8];
#pragma unroll
    for (int j = 0; j < 8; ++j) {
      const int n = j * 16 + l15;
      const bf16x8 k0 = *(const bf16x8*)(&Ksm[(n * 8 + (quad ^ (n & 7))) * 8]);
      const bf16x8 k1 = *(const bf16x8*)(&Ksm[(n * 8 + ((4 + quad) ^ (n & 7))) * 8]);
      sc[0][j] = MFMA16(a[0][0], k0, fz);
      sc[0][j] = MFMA16(a[0][1], k1, sc[0][j]);
      sc[1][j] = MFMA16(a[1][0], k0, fz);
      sc[1][j] = MFMA16(a[1][1], k1, sc[1][j]);
    }

    bf16* ps = &Psm[w][0];
#pragma unroll
    for (int qt = 0; qt < 2; ++qt) {
      // exp2 + write P (C layout -> swizzled [16][128] A-readable layout)
#pragma unroll
      for (int r = 0; r < 4; ++r) {
        const int prow = quad * 4 + r;
        float sum = 0.f;
#pragma unroll
        for (int j = 0; j < 8; ++j) {
          const float p = EXP2F(sc[qt][j][r]);
          sum += p;
          const int col = j * 16 + l15;
          const int cc = col >> 3;
          const int ccs = (cc & 8) | ((cc & 7) ^ (prow & 7));
          ps[prow * 128 + ccs * 8 + (col & 7)] = (bf16)p;
        }
        l_i[qt][r] += sum;
      }
      // P @ V
#pragma unroll
      for (int c32 = 0; c32 < 4; ++c32) {
        const int pc = c32 * 4 + quad;
        const int pcs = (pc & 8) | ((pc & 7) ^ (l15 & 7));
        const bf16x8 pf = *(const bf16x8*)(ps + l15 * 128 + pcs * 8);
#pragma unroll
        for (int ni = 0; ni < 4; ++ni) {
          const int d = ni * 16 + l15;
          const int vcs = (pc & 8) | ((pc & 7) ^ (d & 7));
          const bf16x8 vf = *(const bf16x8*)(&Vsm[(d * 16 + vcs) * 8]);
          o[qt][ni] = MFMA16(pf, vf, o[qt][ni]);
        }
      }
    }
    __syncthreads();
  }

#pragma unroll
  for (int qt = 0; qt < 2; ++qt) {
#pragma unroll
    for (int r = 0; r < 4; ++r) {
      float l = l_i[qt][r];
      l += __shfl_xor(l, 1);
      l += __shfl_xor(l, 2);
      l += __shfl_xor(l, 4);
      l += __shfl_xor(l, 8);
      const float inv = 1.0f / l;
#pragma unroll
      for (int ni = 0; ni < 4; ++ni)
        ctx[base + (size_t)(qbase + qt * 16 + quad * 4 + r) * 64 + ni * 16 + l15]
            = (bf16)(o[qt][ni][r] * inv);
    }
  }
}

// ---------------------------------------------------------------------------
// z = mu + exp(sig_raw) * eps from fused [8192,256] mu|sig buffer.
__global__ __launch_bounds__(256) void final_kernel(const float* __restrict__ musg,
                                                    const float* __restrict__ eps,
                                                    float* __restrict__ z) {
  const int i = blockIdx.x * 256 + threadIdx.x;
  const int row = i >> 5;
  const int c = (i & 31) * 4;
  const float4 m = *(const float4*)(musg + (size_t)row * 256 + c);
  const float4 s = *(const float4*)(musg + (size_t)row * 256 + 128 + c);
  const float4 e = *(const float4*)(eps + (size_t)row * 128 + c);
  float4 r;
  r.x = m.x + __expf(s.x) * e.x;
  r.y = m.y + __expf(s.y) * e.y;
  r.z = m.z + __expf(s.z) * e.z;
  r.w = m.w + __expf(s.w) * e.w;
  *(float4*)(z + (size_t)row * 128 + c) = r;
}

// ---------------------------------------------------------------------------
extern "C" void kernel_launch(void* const* d_in, const int* in_sizes, int n_in,
                              void* d_out, int out_size, void* d_ws, size_t ws_size,
                              hipStream_t stream) {
  (void)in_sizes; (void)n_in; (void)out_size; (void)ws_size;
  const int* x = (const int*)d_in[0];
  const float* emb = (const float*)d_in[1];
  const float* Wq = (const float*)d_in[2];
  const float* bq = (const float*)d_in[3];
  const float* Wk = (const float*)d_in[4];
  const float* bkb = (const float*)d_in[5];
  const float* Wv = (const float*)d_in[6];
  const float* bv = (const float*)d_in[7];
  const float* Wo = (const float*)d_in[8];
  const float* bo = (const float*)d_in[9];
  const float* g1 = (const float*)d_in[10];
  const float* be1 = (const float*)d_in[11];
  const float* W1 = (const float*)d_in[12];
  const float* bf1 = (const float*)d_in[13];
  const float* W2 = (const float*)d_in[14];
  const float* bf2 = (const float*)d_in[15];
  const float* g2 = (const float*)d_in[16];
  const float* be2 = (const float*)d_in[17];
  const float* g3 = (const float*)d_in[18];
  const float* be3 = (const float*)d_in[19];
  const float* Wmu = (const float*)d_in[20];
  const float* bmu = (const float*)d_in[21];
  const float* Wsig = (const float*)d_in[22];
  const float* bsig = (const float*)d_in[23];
  const float* eps = (const float*)d_in[24];
  float* z = (float*)d_out;

  const int M = 8192, D = 1024;
  char* ws = (char*)d_ws;
  size_t off = 0;
  auto alloc = [&](size_t b) {
    char* p = ws + off;
    off += (b + 255) & ~(size_t)255;
    return p;
  };
  bf16* wqT = (bf16*)alloc((size_t)1024 * 1024 * 2);
  bf16* wkT = (bf16*)alloc((size_t)1024 * 1024 * 2);
  bf16* wvT = (bf16*)alloc((size_t)1024 * 1024 * 2);
  bf16* woT = (bf16*)alloc((size_t)1024 * 1024 * 2);
  bf16* w1T = (bf16*)alloc((size_t)1024 * 1024 * 2);
  bf16* w2T = (bf16*)alloc((size_t)1024 * 1024 * 2);
  bf16* wmsT = (bf16*)alloc((size_t)256 * 1024 * 2);   // [Wmu^T ; Wsig^T]
  float* hA = (float*)alloc((size_t)M * D * 4);        // h1_f32 -> h2 -> h4
  bf16* hb = (bf16*)alloc((size_t)M * D * 2);          // h1/h3/h5 bf16; VtG between
  bf16* Qb = (bf16*)alloc((size_t)M * D * 2);          // Q -> ffn hidden
  bf16* Kb = (bf16*)alloc((size_t)M * D * 2);
  bf16* Vb = (bf16*)alloc((size_t)M * D * 2);
  bf16* Cb = (bf16*)alloc((size_t)M * D * 2);          // ctx; later mu|sig f32
  bf16* VtG = hb;                                      // same 16.78MB size; hb free
                                                       // between QKV gemms and LN2
  float* musg = (float*)Cb;                            // [8192,256] f32 = 8 MB

  dim3 b256(256);
  TP6 tp;
  tp.src[0] = Wq; tp.dst[0] = wqT;
  tp.src[1] = Wk; tp.dst[1] = wkT;
  tp.src[2] = Wv; tp.dst[2] = wvT;
  tp.src[3] = Wo; tp.dst[3] = woT;
  tp.src[4] = W1; tp.dst[4] = w1T;
  tp.src[5] = W2; tp.dst[5] = w2T;
  transpose6_kernel<<<dim3(16, 16, 6), b256, 0, stream>>>(tp);
  transpose_kernel<<<dim3(16, 2), b256, 0, stream>>>(Wmu, wmsT, 1024, 128);
  transpose_kernel<<<dim3(16, 2), b256, 0, stream>>>(Wsig, wmsT + (size_t)128 * 1024, 1024, 128);

  embed_ln_kernel<<<8192, b256, 0, stream>>>(x, emb, g1, be1, hb, hA);  // h1

  gemm_kernel<0><<<dim3(64, 8), b256, 0, stream>>>(hb, wqT, bq, Qb, nullptr, M, D, D);
  gemm_kernel<0><<<dim3(64, 8), b256, 0, stream>>>(hb, wkT, bkb, Kb, nullptr, M, D, D);
  gemm_kernel<0><<<dim3(64, 8), b256, 0, stream>>>(hb, wvT, bv, Vb, nullptr, M, D, D);

  vtrans_kernel<<<dim3(256, 8), b256, 0, stream>>>(Vb, VtG);
  attn_kernel<<<dim3(256, 4), b256, 0, stream>>>(Qb, Kb, VtG, Cb);

  gemm_kernel<1><<<dim3(64, 8), b256, 0, stream>>>(Cb, woT, bo, hA, hA, M, D, D); // h2
  ln_kernel<<<8192, b256, 0, stream>>>(hA, g2, be2, hb, nullptr);                 // h3
  gemm_kernel<2><<<dim3(64, 8), b256, 0, stream>>>(hb, w1T, bf1, Qb, nullptr, M, D, D);
  gemm_kernel<3><<<dim3(64, 8), b256, 0, stream>>>(Qb, w2T, bf2, hA, nullptr, M, D, D); // h4=2f
  ln_kernel<<<8192, b256, 0, stream>>>(hA, g3, be3, hb, nullptr);                 // h5
  gemm_kernel<5><<<dim3(64, 2), b256, 0, stream>>>(hb, wmsT, bmu, musg, bsig, M, 256, D);
  final_kernel<<<1024, b256, 0, stream>>>(musg, eps, z);
}

// Round 3
// 445.932 us; speedup vs baseline: 1.3213x; 1.1366x over previous
//
#include <hip/hip_runtime.h>
#include <cstdint>

// FirstEncoder: B=16 S=512 D=1024 H=16 L=128 V=32000, DH=64.
// Faithful: raw-reshape head split (head (b,h) = contiguous [512,64] block of
// the flat [8192,1024] buffer), score scale 1/32 (DH/2), FFN residual f+f=2f.

typedef __bf16 bf16;
typedef __bf16 bf16x8 __attribute__((ext_vector_type(8)));
typedef __bf16 bf16x4 __attribute__((ext_vector_type(4)));
typedef float f32x4 __attribute__((ext_vector_type(4)));

#define MFMA16(a, b, c) __builtin_amdgcn_mfma_f32_16x16x32_bf16((a), (b), (c), 0, 0, 0)

#if __has_builtin(__builtin_amdgcn_exp2f)
#define EXP2F(x) __builtin_amdgcn_exp2f(x)
#else
#define EXP2F(x) exp2f(x)
#endif

// async 16B global->LDS (lane i lands at wave-uniform base + i*16)
__device__ __forceinline__ void async16(const bf16* g, bf16* l) {
  __builtin_amdgcn_global_load_lds(
      (const __attribute__((address_space(1))) unsigned int*)g,
      (__attribute__((address_space(3))) unsigned int*)l, 16, 0, 0);
}

// ---------------------------------------------------------------------------
// 8x fused weight transpose + f32->bf16. All have K=1024 rows; N = 1024 for
// the six D x D weights, 128 for Wmu/Wsig. Wt[n*1024 + k] = W[k*N + n].
struct TP8 {
  const float* src[8];
  bf16* dst[8];
  int ncol[8];
};
__global__ __launch_bounds__(256) void transpose8_kernel(TP8 p) {
  const int z = blockIdx.z;
  const int N = p.ncol[z];
  const int tk = blockIdx.x * 64, tn = blockIdx.y * 64;
  if (tn >= N) return;
  const float* __restrict__ W = p.src[z];
  bf16* __restrict__ Wt = p.dst[z];
  __shared__ float tile[64][65];
  const int a = threadIdx.x >> 6, b = threadIdx.x & 63;
#pragma unroll
  for (int i = 0; i < 16; ++i) {
    int k = a + i * 4;
    tile[k][b] = W[(size_t)(tk + k) * N + tn + b];
  }
  __syncthreads();
#pragma unroll
  for (int i = 0; i < 16; ++i) {
    int n = a + i * 4;
    Wt[(size_t)(tn + n) * 1024 + tk + b] = (bf16)tile[b][n];
  }
}

// ---------------------------------------------------------------------------
// Fused embed (*32 + posenc) + LayerNorm1 -> bf16 h1.
__global__ __launch_bounds__(256) void embed_ln_kernel(const int* __restrict__ x,
                                                       const float* __restrict__ emb,
                                                       const float* __restrict__ g,
                                                       const float* __restrict__ be,
                                                       bf16* __restrict__ obf) {
  const int row = blockIdx.x;
  const int s = row & 511;
  const int t = x[row];
  const int tid = threadIdx.x;
  const int c = tid * 4;
  const float4 e = *(const float4*)(emb + (size_t)t * 1024 + c);
  const float ev[4] = {e.x, e.y, e.z, e.w};
  float o[4];
#pragma unroll
  for (int j = 0; j < 4; ++j) {
    int cc = c + j;
    float freq = __expf((float)(cc & ~1) * (-9.210340371976184f / 1024.0f));
    float ang = (float)s * freq;
    float pe = (cc & 1) ? cosf(ang) : sinf(ang);
    o[j] = ev[j] * 32.0f + pe;
  }
  float sm = o[0] + o[1] + o[2] + o[3];
  float q = o[0] * o[0] + o[1] * o[1] + o[2] * o[2] + o[3] * o[3];
#pragma unroll
  for (int off = 32; off > 0; off >>= 1) {
    sm += __shfl_down(sm, off);
    q += __shfl_down(q, off);
  }
  __shared__ float rs[4], rq[4];
  const int w = tid >> 6, lane = tid & 63;
  if (lane == 0) { rs[w] = sm; rq[w] = q; }
  __syncthreads();
  const float S = rs[0] + rs[1] + rs[2] + rs[3];
  const float Qs = rq[0] + rq[1] + rq[2] + rq[3];
  const float mean = S * (1.0f / 1024.0f);
  const float var = Qs * (1.0f / 1024.0f) - mean * mean;
  const float rstd = rsqrtf(var + 1e-5f);
  const float4 gv = ((const float4*)g)[tid];
  const float4 bv = ((const float4*)be)[tid];
  const float gvv[4] = {gv.x, gv.y, gv.z, gv.w};
  const float bvv[4] = {bv.x, bv.y, bv.z, bv.w};
  bf16x4 ob;
#pragma unroll
  for (int j = 0; j < 4; ++j) ob[j] = (bf16)((o[j] - mean) * rstd * gvv[j] + bvv[j]);
  ((bf16x4*)(obf + (size_t)row * 1024))[tid] = ob;
}

// ---------------------------------------------------------------------------
// LayerNorm over D=1024, bf16 in -> bf16 out.
__global__ __launch_bounds__(256) void ln_kernel(const bf16* __restrict__ in,
                                                 const float* __restrict__ g,
                                                 const float* __restrict__ be,
                                                 bf16* __restrict__ obf) {
  const int row = blockIdx.x;
  const int tid = threadIdx.x;
  const bf16x4 v4 = ((const bf16x4*)(in + (size_t)row * 1024))[tid];
  float v[4];
#pragma unroll
  for (int j = 0; j < 4; ++j) v[j] = (float)v4[j];
  float s = v[0] + v[1] + v[2] + v[3];
  float q = v[0] * v[0] + v[1] * v[1] + v[2] * v[2] + v[3] * v[3];
#pragma unroll
  for (int off = 32; off > 0; off >>= 1) {
    s += __shfl_down(s, off);
    q += __shfl_down(q, off);
  }
  __shared__ float rs[4], rq[4];
  const int w = tid >> 6, lane = tid & 63;
  if (lane == 0) { rs[w] = s; rq[w] = q; }
  __syncthreads();
  const float S = rs[0] + rs[1] + rs[2] + rs[3];
  const float Qs = rq[0] + rq[1] + rq[2] + rq[3];
  const float mean = S * (1.0f / 1024.0f);
  const float var = Qs * (1.0f / 1024.0f) - mean * mean;
  const float rstd = rsqrtf(var + 1e-5f);
  const float4 gv = ((const float4*)g)[tid];
  const float4 bv = ((const float4*)be)[tid];
  const float gvv[4] = {gv.x, gv.y, gv.z, gv.w};
  const float bvv[4] = {bv.x, bv.y, bv.z, bv.w};
  bf16x4 ob;
#pragma unroll
  for (int j = 0; j < 4; ++j) ob[j] = (bf16)((v[j] - mean) * rstd * gvv[j] + bvv[j]);
  ((bf16x4*)(obf + (size_t)row * 1024))[tid] = ob;
}

// ---------------------------------------------------------------------------
// GEMM: C[M,N] = A[M,K](bf16) @ Bt[N,K]^T(bf16) + bias.
// Single-barrier double-buffered K-loop: ds_read(cur) -> async(next) -> MFMA
// -> __syncthreads(). global_load_lds width-16 + XOR-swizzled LDS chunks.
// MODE 1: bf16 out = acc + b0 + resid(bf16)         (Wo)
// MODE 2: bf16 out = leaky_relu(acc + b0)           (W1)
// MODE 3: bf16 out = 2*(acc + b0)                   (W2, f+f)
// MODE 5: f32  out = acc + (col<128 ? b0 : b1)      (mu|sig, N=256)
// MODE 6: bf16 out routed to o0/o1/o2 by n-part     (fused QKV, N=3072)
template <int MODE>
__global__ __launch_bounds__(256) void gemm_kernel(
    const bf16* __restrict__ A, const bf16* __restrict__ Bt,
    const float* __restrict__ b0f, const float* __restrict__ b1f,
    const float* __restrict__ b2f,
    bf16* __restrict__ o0, bf16* __restrict__ o1, bf16* __restrict__ o2,
    float* __restrict__ of, const bf16* __restrict__ residb,
    int M, int N, int K) {
  __shared__ __attribute__((aligned(16))) bf16 Asm[2][128 * 32];
  __shared__ __attribute__((aligned(16))) bf16 Bsm[2][128 * 32];
  const int tid = threadIdx.x;
  const int wv = tid >> 6, lane = tid & 63;
  const int quad = lane >> 4, l15 = lane & 15;
  const int m0 = blockIdx.x * 128, n0 = blockIdx.y * 128;
  const int wm = wv & 1, wn = wv >> 1;

  f32x4 acc[4][4];
#pragma unroll
  for (int i = 0; i < 4; ++i)
#pragma unroll
    for (int j = 0; j < 4; ++j) acc[i][j] = {0.f, 0.f, 0.f, 0.f};

  // chunk slot s (16B) at LDS slot s; global chunk col = (s&3) ^ ((row>>1)&3)
  const int r0 = tid >> 2, c0 = ((tid & 3) ^ ((r0 >> 1) & 3)) * 8;
  const int r1 = (tid + 256) >> 2, c1 = ((tid & 3) ^ ((r1 >> 1) & 3)) * 8;
  const bf16* Ag0 = A + (size_t)(m0 + r0) * K + c0;
  const bf16* Ag1 = A + (size_t)(m0 + r1) * K + c1;
  const bf16* Bg0 = Bt + (size_t)(n0 + r0) * K + c0;
  const bf16* Bg1 = Bt + (size_t)(n0 + r1) * K + c1;

  // prologue: fill buffer 0
  async16(Ag0, &Asm[0][tid * 8]);
  async16(Ag1, &Asm[0][(tid + 256) * 8]);
  async16(Bg0, &Bsm[0][tid * 8]);
  async16(Bg1, &Bsm[0][(tid + 256) * 8]);
  __syncthreads();

  const int nk = K >> 5;
  for (int k = 0; k < nk; ++k) {
    const int cur = k & 1, nxt = cur ^ 1;
    bf16x8 af[4], bfr[4];
#pragma unroll
    for (int mi = 0; mi < 4; ++mi) {
      const int row = wm * 64 + mi * 16 + l15;
      af[mi] = *(const bf16x8*)(&Asm[cur][(row * 4 + (quad ^ ((row >> 1) & 3))) * 8]);
    }
#pragma unroll
    for (int ni = 0; ni < 4; ++ni) {
      const int row = wn * 64 + ni * 16 + l15;
      bfr[ni] = *(const bf16x8*)(&Bsm[cur][(row * 4 + (quad ^ ((row >> 1) & 3))) * 8]);
    }
    if (k + 1 < nk) {
      const int ko = (k + 1) * 32;
      async16(Ag0 + ko, &Asm[nxt][tid * 8]);
      async16(Ag1 + ko, &Asm[nxt][(tid + 256) * 8]);
      async16(Bg0 + ko, &Bsm[nxt][tid * 8]);
      async16(Bg1 + ko, &Bsm[nxt][(tid + 256) * 8]);
    }
#pragma unroll
    for (int mi = 0; mi < 4; ++mi)
#pragma unroll
      for (int ni = 0; ni < 4; ++ni)
        acc[mi][ni] = MFMA16(af[mi], bfr[ni], acc[mi][ni]);
    __syncthreads();
  }

  // epilogue
  const int part = (MODE == 6) ? (blockIdx.y >> 3) : 0;
  bf16* ob = o0;
  const float* bp = b0f;
  if constexpr (MODE == 6) {
    ob = (part == 0) ? o0 : (part == 1 ? o1 : o2);
    bp = (part == 0) ? b0f : (part == 1 ? b1f : b2f);
  }
#pragma unroll
  for (int ni = 0; ni < 4; ++ni) {
    const int col = n0 + wn * 64 + ni * 16 + l15;
    const int cl = (MODE == 6) ? (col - part * 1024) : col;
    float bv;
    if constexpr (MODE == 5)
      bv = (col < 128) ? b0f[col] : b1f[col - 128];
    else
      bv = bp[cl];
#pragma unroll
    for (int mi = 0; mi < 4; ++mi) {
#pragma unroll
      for (int r = 0; r < 4; ++r) {
        const int row = m0 + wm * 64 + mi * 16 + quad * 4 + r;
        float v = acc[mi][ni][r] + bv;
        if constexpr (MODE == 1) {
          const size_t idx = (size_t)row * N + col;
          o0[idx] = (bf16)(v + (float)residb[idx]);
        } else if constexpr (MODE == 2) {
          o0[(size_t)row * N + col] = (bf16)(v > 0.f ? v : 0.01f * v);
        } else if constexpr (MODE == 3) {
          o0[(size_t)row * N + col] = (bf16)(2.0f * v);
        } else if constexpr (MODE == 5) {
          of[(size_t)row * N + col] = v;
        } else {  // MODE 6
          ob[(size_t)row * 1024 + cl] = (bf16)v;
        }
      }
    }
  }
}

// ---------------------------------------------------------------------------
// V transpose per head: Vb flat [256 bh][512 kv][64 d] -> VtG [256 bh][64 d][512 kv]
__global__ __launch_bounds__(256) void vtrans_kernel(const bf16* __restrict__ Vb,
                                                     bf16* __restrict__ VtG) {
  __shared__ float t[64][65];
  const int bh = blockIdx.x, kt = blockIdx.y;
  const int tid = threadIdx.x;
  const bf16* src = Vb + (size_t)bh * 32768 + (size_t)kt * 4096;
#pragma unroll
  for (int i = 0; i < 2; ++i) {
    int s = i * 256 + tid;
    int r = s >> 3, c = (s & 7) * 8;
    bf16x8 v = *(const bf16x8*)(src + (size_t)s * 8);
#pragma unroll
    for (int j = 0; j < 8; ++j) t[r][c + j] = (float)v[j];
  }
  __syncthreads();
  bf16* dst = VtG + (size_t)bh * 32768 + kt * 64;
#pragma unroll
  for (int i = 0; i < 2; ++i) {
    int s = i * 256 + tid;
    int d = s >> 3, kc = (s & 7) * 8;
    bf16 tmp[8];
#pragma unroll
    for (int j = 0; j < 8; ++j) tmp[j] = (bf16)t[kc + j][d];
    *(uint4*)(dst + (size_t)d * 512 + kc) = *(const uint4*)tmp;
  }
}

// ---------------------------------------------------------------------------
// Flash-style attention. grid (256 bh, 4 qblk), 256 threads (4 waves).
// No-max softmax (|score/32| small): p = exp2(score * log2e/32) via Q prescale.
__global__ __launch_bounds__(256) void attn_kernel(const bf16* __restrict__ Qg,
                                                   const bf16* __restrict__ Kg,
                                                   const bf16* __restrict__ Vt,
                                                   bf16* __restrict__ ctx) {
  __shared__ __attribute__((aligned(16))) bf16 Ksm[128 * 64];
  __shared__ __attribute__((aligned(16))) bf16 Vsm[64 * 128];
  __shared__ __attribute__((aligned(16))) bf16 Psm[4][16 * 128];
  const int tid = threadIdx.x;
  const int w = tid >> 6, lane = tid & 63;
  const int quad = lane >> 4, l15 = lane & 15;
  const int bh = blockIdx.x;
  const size_t base = (size_t)bh * 32768;
  const bf16* Vth = Vt + base;
  const int qbase = blockIdx.y * 128 + w * 32;
  const f32x4 fz = {0.f, 0.f, 0.f, 0.f};

  bf16x8 a[2][2];
#pragma unroll
  for (int qt = 0; qt < 2; ++qt)
#pragma unroll
    for (int hf = 0; hf < 2; ++hf) {
      bf16x8 tq = *(const bf16x8*)(Qg + base +
                   (size_t)(qbase + qt * 16 + l15) * 64 + hf * 32 + quad * 8);
#pragma unroll
      for (int e = 0; e < 8; ++e) tq[e] = (bf16)((float)tq[e] * 0.045111758f);
      a[qt][hf] = tq;
    }

  f32x4 o[2][4];
  float l_i[2][4];
#pragma unroll
  for (int qt = 0; qt < 2; ++qt)
#pragma unroll
    for (int i = 0; i < 4; ++i) { o[qt][i] = fz; l_i[qt][i] = 0.f; }

  for (int kv0 = 0; kv0 < 512; kv0 += 128) {
#pragma unroll
    for (int i = 0; i < 4; ++i) {
      int s = i * 256 + tid;
      int r = s >> 3, c = (s & 7) ^ (r & 7);
      async16(Kg + base + (size_t)(kv0 + r) * 64 + c * 8, &Ksm[s * 8]);
    }
#pragma unroll
    for (int i = 0; i < 4; ++i) {
      int s = i * 256 + tid;
      int d = s >> 4, cs = s & 15;
      int c = (cs & 8) | ((cs & 7) ^ (d & 7));
      async16(Vth + (size_t)d * 512 + kv0 + c * 8, &Vsm[s * 8]);
    }
    __syncthreads();

    f32x4 sc[2][8];
#pragma unroll
    for (int j = 0; j < 8; ++j) {
      const int n = j * 16 + l15;
      const bf16x8 k0 = *(const bf16x8*)(&Ksm[(n * 8 + (quad ^ (n & 7))) * 8]);
      const bf16x8 k1 = *(const bf16x8*)(&Ksm[(n * 8 + ((4 + quad) ^ (n & 7))) * 8]);
      sc[0][j] = MFMA16(a[0][0], k0, fz);
      sc[0][j] = MFMA16(a[0][1], k1, sc[0][j]);
      sc[1][j] = MFMA16(a[1][0], k0, fz);
      sc[1][j] = MFMA16(a[1][1], k1, sc[1][j]);
    }

    bf16* ps = &Psm[w][0];
#pragma unroll
    for (int qt = 0; qt < 2; ++qt) {
#pragma unroll
      for (int r = 0; r < 4; ++r) {
        const int prow = quad * 4 + r;
        float sum = 0.f;
#pragma unroll
        for (int j = 0; j < 8; ++j) {
          const float p = EXP2F(sc[qt][j][r]);
          sum += p;
          const int col = j * 16 + l15;
          const int cc = col >> 3;
          const int ccs = (cc & 8) | ((cc & 7) ^ (prow & 7));
          ps[prow * 128 + ccs * 8 + (col & 7)] = (bf16)p;
        }
        l_i[qt][r] += sum;
      }
#pragma unroll
      for (int c32 = 0; c32 < 4; ++c32) {
        const int pc = c32 * 4 + quad;
        const int pcs = (pc & 8) | ((pc & 7) ^ (l15 & 7));
        const bf16x8 pf = *(const bf16x8*)(ps + l15 * 128 + pcs * 8);
#pragma unroll
        for (int ni = 0; ni < 4; ++ni) {
          const int d = ni * 16 + l15;
          const int vcs = (pc & 8) | ((pc & 7) ^ (d & 7));
          const bf16x8 vf = *(const bf16x8*)(&Vsm[(d * 16 + vcs) * 8]);
          o[qt][ni] = MFMA16(pf, vf, o[qt][ni]);
        }
      }
    }
    __syncthreads();
  }

#pragma unroll
  for (int qt = 0; qt < 2; ++qt) {
#pragma unroll
    for (int r = 0; r < 4; ++r) {
      float l = l_i[qt][r];
      l += __shfl_xor(l, 1);
      l += __shfl_xor(l, 2);
      l += __shfl_xor(l, 4);
      l += __shfl_xor(l, 8);
      const float inv = 1.0f / l;
#pragma unroll
      for (int ni = 0; ni < 4; ++ni)
        ctx[base + (size_t)(qbase + qt * 16 + quad * 4 + r) * 64 + ni * 16 + l15]
            = (bf16)(o[qt][ni][r] * inv);
    }
  }
}

// ---------------------------------------------------------------------------
// z = mu + exp(sig_raw) * eps from fused [8192,256] mu|sig buffer.
__global__ __launch_bounds__(256) void final_kernel(const float* __restrict__ musg,
                                                    const float* __restrict__ eps,
                                                    float* __restrict__ z) {
  const int i = blockIdx.x * 256 + threadIdx.x;
  const int row = i >> 5;
  const int c = (i & 31) * 4;
  const float4 m = *(const float4*)(musg + (size_t)row * 256 + c);
  const float4 s = *(const float4*)(musg + (size_t)row * 256 + 128 + c);
  const float4 e = *(const float4*)(eps + (size_t)row * 128 + c);
  float4 r;
  r.x = m.x + __expf(s.x) * e.x;
  r.y = m.y + __expf(s.y) * e.y;
  r.z = m.z + __expf(s.z) * e.z;
  r.w = m.w + __expf(s.w) * e.w;
  *(float4*)(z + (size_t)row * 128 + c) = r;
}

// ---------------------------------------------------------------------------
extern "C" void kernel_launch(void* const* d_in, const int* in_sizes, int n_in,
                              void* d_out, int out_size, void* d_ws, size_t ws_size,
                              hipStream_t stream) {
  (void)in_sizes; (void)n_in; (void)out_size; (void)ws_size;
  const int* x = (const int*)d_in[0];
  const float* emb = (const float*)d_in[1];
  const float* Wq = (const float*)d_in[2];
  const float* bq = (const float*)d_in[3];
  const float* Wk = (const float*)d_in[4];
  const float* bkb = (const float*)d_in[5];
  const float* Wv = (const float*)d_in[6];
  const float* bv = (const float*)d_in[7];
  const float* Wo = (const float*)d_in[8];
  const float* bo = (const float*)d_in[9];
  const float* g1 = (const float*)d_in[10];
  const float* be1 = (const float*)d_in[11];
  const float* W1 = (const float*)d_in[12];
  const float* bf1 = (const float*)d_in[13];
  const float* W2 = (const float*)d_in[14];
  const float* bf2 = (const float*)d_in[15];
  const float* g2 = (const float*)d_in[16];
  const float* be2 = (const float*)d_in[17];
  const float* g3 = (const float*)d_in[18];
  const float* be3 = (const float*)d_in[19];
  const float* Wmu = (const float*)d_in[20];
  const float* bmu = (const float*)d_in[21];
  const float* Wsig = (const float*)d_in[22];
  const float* bsig = (const float*)d_in[23];
  const float* eps = (const float*)d_in[24];
  float* z = (float*)d_out;

  const int M = 8192, D = 1024;
  char* ws = (char*)d_ws;
  size_t off = 0;
  auto alloc = [&](size_t b) {
    char* p = ws + off;
    off += (b + 255) & ~(size_t)255;
    return p;
  };
  bf16* wqkvT = (bf16*)alloc((size_t)3072 * 1024 * 2);  // [wq^T; wk^T; wv^T]
  bf16* woT = (bf16*)alloc((size_t)1024 * 1024 * 2);
  bf16* w1T = (bf16*)alloc((size_t)1024 * 1024 * 2);
  bf16* w2T = (bf16*)alloc((size_t)1024 * 1024 * 2);
  bf16* wmsT = (bf16*)alloc((size_t)256 * 1024 * 2);    // [Wmu^T ; Wsig^T]
  bf16* hb = (bf16*)alloc((size_t)M * D * 2);           // h1 (resid for Wo)
  bf16* Qb = (bf16*)alloc((size_t)M * D * 2);
  bf16* Kb = (bf16*)alloc((size_t)M * D * 2);
  bf16* Vb = (bf16*)alloc((size_t)M * D * 2);
  bf16* VtG = (bf16*)alloc((size_t)M * D * 2);
  bf16* Cb = (bf16*)alloc((size_t)M * D * 2);           // ctx
  bf16* h2b = (bf16*)alloc((size_t)M * D * 2);
  bf16* h3b = (bf16*)alloc((size_t)M * D * 2);
  bf16* hidb = (bf16*)alloc((size_t)M * D * 2);
  bf16* h4b = (bf16*)alloc((size_t)M * D * 2);
  bf16* h5b = (bf16*)alloc((size_t)M * D * 2);
  float* musg = (float*)alloc((size_t)M * 256 * 4);     // [8192,256] f32

  dim3 b256(256);
  TP8 tp;
  tp.src[0] = Wq;   tp.dst[0] = wqkvT;                        tp.ncol[0] = 1024;
  tp.src[1] = Wk;   tp.dst[1] = wqkvT + (size_t)1024 * 1024;  tp.ncol[1] = 1024;
  tp.src[2] = Wv;   tp.dst[2] = wqkvT + (size_t)2048 * 1024;  tp.ncol[2] = 1024;
  tp.src[3] = Wo;   tp.dst[3] = woT;                          tp.ncol[3] = 1024;
  tp.src[4] = W1;   tp.dst[4] = w1T;                          tp.ncol[4] = 1024;
  tp.src[5] = W2;   tp.dst[5] = w2T;                          tp.ncol[5] = 1024;
  tp.src[6] = Wmu;  tp.dst[6] = wmsT;                         tp.ncol[6] = 128;
  tp.src[7] = Wsig; tp.dst[7] = wmsT + (size_t)128 * 1024;    tp.ncol[7] = 128;
  transpose8_kernel<<<dim3(16, 16, 8), b256, 0, stream>>>(tp);

  embed_ln_kernel<<<8192, b256, 0, stream>>>(x, emb, g1, be1, hb);  // h1

  // fused QKV: N=3072, outputs routed to Qb/Kb/Vb
  gemm_kernel<6><<<dim3(64, 24), b256, 0, stream>>>(hb, wqkvT, bq, bkb, bv,
                                                    Qb, Kb, Vb, nullptr, nullptr,
                                                    M, 3072, D);
  vtrans_kernel<<<dim3(256, 8), b256, 0, stream>>>(Vb, VtG);
  attn_kernel<<<dim3(256, 4), b256, 0, stream>>>(Qb, Kb, VtG, Cb);

  gemm_kernel<1><<<dim3(64, 8), b256, 0, stream>>>(Cb, woT, bo, nullptr, nullptr,
                                                   h2b, nullptr, nullptr, nullptr, hb,
                                                   M, D, D);
  ln_kernel<<<8192, b256, 0, stream>>>(h2b, g2, be2, h3b);
  gemm_kernel<2><<<dim3(64, 8), b256, 0, stream>>>(h3b, w1T, bf1, nullptr, nullptr,
                                                   hidb, nullptr, nullptr, nullptr, nullptr,
                                                   M, D, D);
  gemm_kernel<3><<<dim3(64, 8), b256, 0, stream>>>(hidb, w2T, bf2, nullptr, nullptr,
                                                   h4b, nullptr, nullptr, nullptr, nullptr,
                                                   M, D, D);
  ln_kernel<<<8192, b256, 0, stream>>>(h4b, g3, be3, h5b);
  gemm_kernel<5><<<dim3(64, 2), b256, 0, stream>>>(h5b, wmsT, bmu, bsig, nullptr,
                                                   nullptr, nullptr, nullptr, musg, nullptr,
                                                   M, 256, D);
  final_kernel<<<1024, b256, 0, stream>>>(musg, eps, z);
}

// Round 4
// 434.080 us; speedup vs baseline: 1.3574x; 1.0273x over previous
//
#include <hip/hip_runtime.h>
#include <cstdint>

// FirstEncoder: B=16 S=512 D=1024 H=16 L=128 V=32000, DH=64.
// Faithful: raw-reshape head split (head (b,h) = contiguous [512,64] block of
// the flat [8192,1024] buffer), score scale 1/32 (DH/2), FFN residual f+f=2f.

typedef __bf16 bf16;
typedef __bf16 bf16x8 __attribute__((ext_vector_type(8)));
typedef __bf16 bf16x4 __attribute__((ext_vector_type(4)));
typedef float f32x4 __attribute__((ext_vector_type(4)));

#define MFMA16(a, b, c) __builtin_amdgcn_mfma_f32_16x16x32_bf16((a), (b), (c), 0, 0, 0)

#if __has_builtin(__builtin_amdgcn_exp2f)
#define EXP2F(x) __builtin_amdgcn_exp2f(x)
#else
#define EXP2F(x) exp2f(x)
#endif

// async 16B global->LDS (lane i lands at wave-uniform base + i*16)
__device__ __forceinline__ void async16(const bf16* g, bf16* l) {
  __builtin_amdgcn_global_load_lds(
      (const __attribute__((address_space(1))) unsigned int*)g,
      (__attribute__((address_space(3))) unsigned int*)l, 16, 0, 0);
}

// ---------------------------------------------------------------------------
// 8x fused weight transpose + f32->bf16. All have K=1024 rows; N = 1024 for
// the six D x D weights, 128 for Wmu/Wsig. Wt[n*1024 + k] = W[k*N + n].
struct TP8 {
  const float* src[8];
  bf16* dst[8];
  int ncol[8];
};
__global__ __launch_bounds__(256) void transpose8_kernel(TP8 p) {
  const int z = blockIdx.z;
  const int N = p.ncol[z];
  const int tk = blockIdx.x * 64, tn = blockIdx.y * 64;
  if (tn >= N) return;
  const float* __restrict__ W = p.src[z];
  bf16* __restrict__ Wt = p.dst[z];
  __shared__ float tile[64][65];
  const int a = threadIdx.x >> 6, b = threadIdx.x & 63;
#pragma unroll
  for (int i = 0; i < 16; ++i) {
    int k = a + i * 4;
    tile[k][b] = W[(size_t)(tk + k) * N + tn + b];
  }
  __syncthreads();
#pragma unroll
  for (int i = 0; i < 16; ++i) {
    int n = a + i * 4;
    Wt[(size_t)(tn + n) * 1024 + tk + b] = (bf16)tile[b][n];
  }
}

// ---------------------------------------------------------------------------
// Fused embed (*32 + posenc) + LayerNorm1 -> bf16 h1. Fast sin/cos (abs err
// ~2e-4, threshold is 0.935 -> irrelevant).
__global__ __launch_bounds__(256) void embed_ln_kernel(const int* __restrict__ x,
                                                       const float* __restrict__ emb,
                                                       const float* __restrict__ g,
                                                       const float* __restrict__ be,
                                                       bf16* __restrict__ obf) {
  const int row = blockIdx.x;
  const int s = row & 511;
  const int t = x[row];
  const int tid = threadIdx.x;
  const int c = tid * 4;
  const float4 e = *(const float4*)(emb + (size_t)t * 1024 + c);
  const float ev[4] = {e.x, e.y, e.z, e.w};
  float o[4];
#pragma unroll
  for (int j = 0; j < 4; ++j) {
    int cc = c + j;
    float freq = __expf((float)(cc & ~1) * (-9.210340371976184f / 1024.0f));
    float ang = (float)s * freq;
    float pe = (cc & 1) ? __cosf(ang) : __sinf(ang);
    o[j] = ev[j] * 32.0f + pe;
  }
  float sm = o[0] + o[1] + o[2] + o[3];
  float q = o[0] * o[0] + o[1] * o[1] + o[2] * o[2] + o[3] * o[3];
#pragma unroll
  for (int off = 32; off > 0; off >>= 1) {
    sm += __shfl_down(sm, off);
    q += __shfl_down(q, off);
  }
  __shared__ float rs[4], rq[4];
  const int w = tid >> 6, lane = tid & 63;
  if (lane == 0) { rs[w] = sm; rq[w] = q; }
  __syncthreads();
  const float S = rs[0] + rs[1] + rs[2] + rs[3];
  const float Qs = rq[0] + rq[1] + rq[2] + rq[3];
  const float mean = S * (1.0f / 1024.0f);
  const float var = Qs * (1.0f / 1024.0f) - mean * mean;
  const float rstd = rsqrtf(var + 1e-5f);
  const float4 gv = ((const float4*)g)[tid];
  const float4 bv = ((const float4*)be)[tid];
  const float gvv[4] = {gv.x, gv.y, gv.z, gv.w};
  const float bvv[4] = {bv.x, bv.y, bv.z, bv.w};
  bf16x4 ob;
#pragma unroll
  for (int j = 0; j < 4; ++j) ob[j] = (bf16)((o[j] - mean) * rstd * gvv[j] + bvv[j]);
  ((bf16x4*)(obf + (size_t)row * 1024))[tid] = ob;
}

// ---------------------------------------------------------------------------
// LayerNorm over D=1024, bf16 in -> bf16 out.
__global__ __launch_bounds__(256) void ln_kernel(const bf16* __restrict__ in,
                                                 const float* __restrict__ g,
                                                 const float* __restrict__ be,
                                                 bf16* __restrict__ obf) {
  const int row = blockIdx.x;
  const int tid = threadIdx.x;
  const bf16x4 v4 = ((const bf16x4*)(in + (size_t)row * 1024))[tid];
  float v[4];
#pragma unroll
  for (int j = 0; j < 4; ++j) v[j] = (float)v4[j];
  float s = v[0] + v[1] + v[2] + v[3];
  float q = v[0] * v[0] + v[1] * v[1] + v[2] * v[2] + v[3] * v[3];
#pragma unroll
  for (int off = 32; off > 0; off >>= 1) {
    s += __shfl_down(s, off);
    q += __shfl_down(q, off);
  }
  __shared__ float rs[4], rq[4];
  const int w = tid >> 6, lane = tid & 63;
  if (lane == 0) { rs[w] = s; rq[w] = q; }
  __syncthreads();
  const float S = rs[0] + rs[1] + rs[2] + rs[3];
  const float Qs = rq[0] + rq[1] + rq[2] + rq[3];
  const float mean = S * (1.0f / 1024.0f);
  const float var = Qs * (1.0f / 1024.0f) - mean * mean;
  const float rstd = rsqrtf(var + 1e-5f);
  const float4 gv = ((const float4*)g)[tid];
  const float4 bv = ((const float4*)be)[tid];
  const float gvv[4] = {gv.x, gv.y, gv.z, gv.w};
  const float bvv[4] = {bv.x, bv.y, bv.z, bv.w};
  bf16x4 ob;
#pragma unroll
  for (int j = 0; j < 4; ++j) ob[j] = (bf16)((v[j] - mean) * rstd * gvv[j] + bvv[j]);
  ((bf16x4*)(obf + (size_t)row * 1024))[tid] = ob;
}

// ---------------------------------------------------------------------------
// GEMM: C[M,N] = A[M,K](bf16) @ Bt[N,K]^T(bf16) + bias.
// Single-barrier double-buffered K-loop, global_load_lds width-16, XOR swizzle.
// BK = 32 (16 KB/buf, 3 blocks/CU for big grids) or 64 (32 KB/buf — used where
// the grid caps occupancy at 2 blocks/CU anyway; halves barrier count).
// MODE 1: bf16 out = acc + b0 + resid(bf16)         (Wo)
// MODE 2: bf16 out = leaky_relu(acc + b0)           (W1)
// MODE 3: bf16 out = 2*(acc + b0)                   (W2, f+f)
// MODE 5: f32  out = acc + (col<128 ? b0 : b1)      (mu|sig, N=256)
// MODE 6: bf16 out routed to o0/o1/o2 by n-part     (fused QKV, N=3072)
template <int MODE, int BK>
__global__ __launch_bounds__(256) void gemm_kernel(
    const bf16* __restrict__ A, const bf16* __restrict__ Bt,
    const float* __restrict__ b0f, const float* __restrict__ b1f,
    const float* __restrict__ b2f,
    bf16* __restrict__ o0, bf16* __restrict__ o1, bf16* __restrict__ o2,
    float* __restrict__ of, const bf16* __restrict__ residb,
    int M, int N, int K) {
  __shared__ __attribute__((aligned(16))) bf16 Asm[2][128 * BK];
  __shared__ __attribute__((aligned(16))) bf16 Bsm[2][128 * BK];
  constexpr int KH = BK / 32;            // k-halves per tile iter
  constexpr int SPT = (128 * BK / 8) / 256;  // 16B slots per thread per matrix
  const int tid = threadIdx.x;
  const int wv = tid >> 6, lane = tid & 63;
  const int quad = lane >> 4, l15 = lane & 15;
  const int m0 = blockIdx.x * 128, n0 = blockIdx.y * 128;
  const int wm = wv & 1, wn = wv >> 1;

  f32x4 acc[4][4];
#pragma unroll
  for (int i = 0; i < 4; ++i)
#pragma unroll
    for (int j = 0; j < 4; ++j) acc[i][j] = {0.f, 0.f, 0.f, 0.f};

  // staging map: slot s -> row, swizzled chunk position
  const bf16* Aglb[SPT];
  const bf16* Bglb[SPT];
  int soff[SPT];
#pragma unroll
  for (int i = 0; i < SPT; ++i) {
    const int s = tid + i * 256;
    int row, col;
    if constexpr (BK == 32) {
      row = s >> 2;
      col = (s & 3) ^ ((row >> 1) & 3);
    } else {
      row = s >> 3;
      col = (s & 7) ^ (row & 7);
    }
    Aglb[i] = A + (size_t)(m0 + row) * K + col * 8;
    Bglb[i] = Bt + (size_t)(n0 + row) * K + col * 8;
    soff[i] = s * 8;
  }

  // prologue: fill buffer 0
#pragma unroll
  for (int i = 0; i < SPT; ++i) async16(Aglb[i], &Asm[0][soff[i]]);
#pragma unroll
  for (int i = 0; i < SPT; ++i) async16(Bglb[i], &Bsm[0][soff[i]]);
  __syncthreads();

  const int nk = K / BK;
  for (int k = 0; k < nk; ++k) {
    const int cur = k & 1, nxt = cur ^ 1;
    bf16x8 af[4][KH], bfr[4][KH];
#pragma unroll
    for (int mi = 0; mi < 4; ++mi) {
      const int row = wm * 64 + mi * 16 + l15;
#pragma unroll
      for (int h = 0; h < KH; ++h) {
        int pos;
        if constexpr (BK == 32) pos = quad ^ ((row >> 1) & 3);
        else pos = (h * 4 + quad) ^ (row & 7);
        af[mi][h] = *(const bf16x8*)(&Asm[cur][(row * (BK / 8) + pos) * 8]);
      }
    }
#pragma unroll
    for (int ni = 0; ni < 4; ++ni) {
      const int row = wn * 64 + ni * 16 + l15;
#pragma unroll
      for (int h = 0; h < KH; ++h) {
        int pos;
        if constexpr (BK == 32) pos = quad ^ ((row >> 1) & 3);
        else pos = (h * 4 + quad) ^ (row & 7);
        bfr[ni][h] = *(const bf16x8*)(&Bsm[cur][(row * (BK / 8) + pos) * 8]);
      }
    }
    if (k + 1 < nk) {
      const int ko = (k + 1) * BK;
#pragma unroll
      for (int i = 0; i < SPT; ++i) async16(Aglb[i] + ko, &Asm[nxt][soff[i]]);
#pragma unroll
      for (int i = 0; i < SPT; ++i) async16(Bglb[i] + ko, &Bsm[nxt][soff[i]]);
    }
#pragma unroll
    for (int h = 0; h < KH; ++h)
#pragma unroll
      for (int mi = 0; mi < 4; ++mi)
#pragma unroll
        for (int ni = 0; ni < 4; ++ni)
          acc[mi][ni] = MFMA16(af[mi][h], bfr[ni][h], acc[mi][ni]);
    __syncthreads();
  }

  // epilogue
  const int part = (MODE == 6) ? (blockIdx.y >> 3) : 0;
  bf16* ob = o0;
  const float* bp = b0f;
  if constexpr (MODE == 6) {
    ob = (part == 0) ? o0 : (part == 1 ? o1 : o2);
    bp = (part == 0) ? b0f : (part == 1 ? b1f : b2f);
  }
#pragma unroll
  for (int ni = 0; ni < 4; ++ni) {
    const int col = n0 + wn * 64 + ni * 16 + l15;
    const int cl = (MODE == 6) ? (col - part * 1024) : col;
    float bv;
    if constexpr (MODE == 5)
      bv = (col < 128) ? b0f[col] : b1f[col - 128];
    else
      bv = bp[cl];
#pragma unroll
    for (int mi = 0; mi < 4; ++mi) {
#pragma unroll
      for (int r = 0; r < 4; ++r) {
        const int row = m0 + wm * 64 + mi * 16 + quad * 4 + r;
        float v = acc[mi][ni][r] + bv;
        if constexpr (MODE == 1) {
          const size_t idx = (size_t)row * N + col;
          o0[idx] = (bf16)(v + (float)residb[idx]);
        } else if constexpr (MODE == 2) {
          o0[(size_t)row * N + col] = (bf16)(v > 0.f ? v : 0.01f * v);
        } else if constexpr (MODE == 3) {
          o0[(size_t)row * N + col] = (bf16)(2.0f * v);
        } else if constexpr (MODE == 5) {
          of[(size_t)row * N + col] = v;
        } else {  // MODE 6
          ob[(size_t)row * 1024 + cl] = (bf16)v;
        }
      }
    }
  }
}

// ---------------------------------------------------------------------------
// V transpose per head: Vb flat [256 bh][512 kv][64 d] -> VtG [256 bh][64 d][512 kv]
__global__ __launch_bounds__(256) void vtrans_kernel(const bf16* __restrict__ Vb,
                                                     bf16* __restrict__ VtG) {
  __shared__ float t[64][65];
  const int bh = blockIdx.x, kt = blockIdx.y;
  const int tid = threadIdx.x;
  const bf16* src = Vb + (size_t)bh * 32768 + (size_t)kt * 4096;
#pragma unroll
  for (int i = 0; i < 2; ++i) {
    int s = i * 256 + tid;
    int r = s >> 3, c = (s & 7) * 8;
    bf16x8 v = *(const bf16x8*)(src + (size_t)s * 8);
#pragma unroll
    for (int j = 0; j < 8; ++j) t[r][c + j] = (float)v[j];
  }
  __syncthreads();
  bf16* dst = VtG + (size_t)bh * 32768 + kt * 64;
#pragma unroll
  for (int i = 0; i < 2; ++i) {
    int s = i * 256 + tid;
    int d = s >> 3, kc = (s & 7) * 8;
    bf16 tmp[8];
#pragma unroll
    for (int j = 0; j < 8; ++j) tmp[j] = (bf16)t[kc + j][d];
    *(uint4*)(dst + (size_t)d * 512 + kc) = *(const uint4*)tmp;
  }
}

// ---------------------------------------------------------------------------
// Flash-style attention. grid (256 bh, 4 qblk), 256 threads (4 waves).
// No-max softmax (|score/32| small): p = exp2(score * log2e/32) via Q prescale.
__global__ __launch_bounds__(256) void attn_kernel(const bf16* __restrict__ Qg,
                                                   const bf16* __restrict__ Kg,
                                                   const bf16* __restrict__ Vt,
                                                   bf16* __restrict__ ctx) {
  __shared__ __attribute__((aligned(16))) bf16 Ksm[128 * 64];
  __shared__ __attribute__((aligned(16))) bf16 Vsm[64 * 128];
  __shared__ __attribute__((aligned(16))) bf16 Psm[4][16 * 128];
  const int tid = threadIdx.x;
  const int w = tid >> 6, lane = tid & 63;
  const int quad = lane >> 4, l15 = lane & 15;
  const int bh = blockIdx.x;
  const size_t base = (size_t)bh * 32768;
  const bf16* Vth = Vt + base;
  const int qbase = blockIdx.y * 128 + w * 32;
  const f32x4 fz = {0.f, 0.f, 0.f, 0.f};

  bf16x8 a[2][2];
#pragma unroll
  for (int qt = 0; qt < 2; ++qt)
#pragma unroll
    for (int hf = 0; hf < 2; ++hf) {
      bf16x8 tq = *(const bf16x8*)(Qg + base +
                   (size_t)(qbase + qt * 16 + l15) * 64 + hf * 32 + quad * 8);
#pragma unroll
      for (int e = 0; e < 8; ++e) tq[e] = (bf16)((float)tq[e] * 0.045111758f);
      a[qt][hf] = tq;
    }

  f32x4 o[2][4];
  float l_i[2][4];
#pragma unroll
  for (int qt = 0; qt < 2; ++qt)
#pragma unroll
    for (int i = 0; i < 4; ++i) { o[qt][i] = fz; l_i[qt][i] = 0.f; }

  for (int kv0 = 0; kv0 < 512; kv0 += 128) {
#pragma unroll
    for (int i = 0; i < 4; ++i) {
      int s = i * 256 + tid;
      int r = s >> 3, c = (s & 7) ^ (r & 7);
      async16(Kg + base + (size_t)(kv0 + r) * 64 + c * 8, &Ksm[s * 8]);
    }
#pragma unroll
    for (int i = 0; i < 4; ++i) {
      int s = i * 256 + tid;
      int d = s >> 4, cs = s & 15;
      int c = (cs & 8) | ((cs & 7) ^ (d & 7));
      async16(Vth + (size_t)d * 512 + kv0 + c * 8, &Vsm[s * 8]);
    }
    __syncthreads();

    f32x4 sc[2][8];
#pragma unroll
    for (int j = 0; j < 8; ++j) {
      const int n = j * 16 + l15;
      const bf16x8 k0 = *(const bf16x8*)(&Ksm[(n * 8 + (quad ^ (n & 7))) * 8]);
      const bf16x8 k1 = *(const bf16x8*)(&Ksm[(n * 8 + ((4 + quad) ^ (n & 7))) * 8]);
      sc[0][j] = MFMA16(a[0][0], k0, fz);
      sc[0][j] = MFMA16(a[0][1], k1, sc[0][j]);
      sc[1][j] = MFMA16(a[1][0], k0, fz);
      sc[1][j] = MFMA16(a[1][1], k1, sc[1][j]);
    }

    bf16* ps = &Psm[w][0];
#pragma unroll
    for (int qt = 0; qt < 2; ++qt) {
#pragma unroll
      for (int r = 0; r < 4; ++r) {
        const int prow = quad * 4 + r;
        float sum = 0.f;
#pragma unroll
        for (int j = 0; j < 8; ++j) {
          const float p = EXP2F(sc[qt][j][r]);
          sum += p;
          const int col = j * 16 + l15;
          const int cc = col >> 3;
          const int ccs = (cc & 8) | ((cc & 7) ^ (prow & 7));
          ps[prow * 128 + ccs * 8 + (col & 7)] = (bf16)p;
        }
        l_i[qt][r] += sum;
      }
#pragma unroll
      for (int c32 = 0; c32 < 4; ++c32) {
        const int pc = c32 * 4 + quad;
        const int pcs = (pc & 8) | ((pc & 7) ^ (l15 & 7));
        const bf16x8 pf = *(const bf16x8*)(ps + l15 * 128 + pcs * 8);
#pragma unroll
        for (int ni = 0; ni < 4; ++ni) {
          const int d = ni * 16 + l15;
          const int vcs = (pc & 8) | ((pc & 7) ^ (d & 7));
          const bf16x8 vf = *(const bf16x8*)(&Vsm[(d * 16 + vcs) * 8]);
          o[qt][ni] = MFMA16(pf, vf, o[qt][ni]);
        }
      }
    }
    __syncthreads();
  }

#pragma unroll
  for (int qt = 0; qt < 2; ++qt) {
#pragma unroll
    for (int r = 0; r < 4; ++r) {
      float l = l_i[qt][r];
      l += __shfl_xor(l, 1);
      l += __shfl_xor(l, 2);
      l += __shfl_xor(l, 4);
      l += __shfl_xor(l, 8);
      const float inv = 1.0f / l;
#pragma unroll
      for (int ni = 0; ni < 4; ++ni)
        ctx[base + (size_t)(qbase + qt * 16 + quad * 4 + r) * 64 + ni * 16 + l15]
            = (bf16)(o[qt][ni][r] * inv);
    }
  }
}

// ---------------------------------------------------------------------------
// z = mu + exp(sig_raw) * eps from fused [8192,256] mu|sig buffer.
__global__ __launch_bounds__(256) void final_kernel(const float* __restrict__ musg,
                                                    const float* __restrict__ eps,
                                                    float* __restrict__ z) {
  const int i = blockIdx.x * 256 + threadIdx.x;
  const int row = i >> 5;
  const int c = (i & 31) * 4;
  const float4 m = *(const float4*)(musg + (size_t)row * 256 + c);
  const float4 s = *(const float4*)(musg + (size_t)row * 256 + 128 + c);
  const float4 e = *(const float4*)(eps + (size_t)row * 128 + c);
  float4 r;
  r.x = m.x + __expf(s.x) * e.x;
  r.y = m.y + __expf(s.y) * e.y;
  r.z = m.z + __expf(s.z) * e.z;
  r.w = m.w + __expf(s.w) * e.w;
  *(float4*)(z + (size_t)row * 128 + c) = r;
}

// ---------------------------------------------------------------------------
extern "C" void kernel_launch(void* const* d_in, const int* in_sizes, int n_in,
                              void* d_out, int out_size, void* d_ws, size_t ws_size,
                              hipStream_t stream) {
  (void)in_sizes; (void)n_in; (void)out_size; (void)ws_size;
  const int* x = (const int*)d_in[0];
  const float* emb = (const float*)d_in[1];
  const float* Wq = (const float*)d_in[2];
  const float* bq = (const float*)d_in[3];
  const float* Wk = (const float*)d_in[4];
  const float* bkb = (const float*)d_in[5];
  const float* Wv = (const float*)d_in[6];
  const float* bv = (const float*)d_in[7];
  const float* Wo = (const float*)d_in[8];
  const float* bo = (const float*)d_in[9];
  const float* g1 = (const float*)d_in[10];
  const float* be1 = (const float*)d_in[11];
  const float* W1 = (const float*)d_in[12];
  const float* bf1 = (const float*)d_in[13];
  const float* W2 = (const float*)d_in[14];
  const float* bf2 = (const float*)d_in[15];
  const float* g2 = (const float*)d_in[16];
  const float* be2 = (const float*)d_in[17];
  const float* g3 = (const float*)d_in[18];
  const float* be3 = (const float*)d_in[19];
  const float* Wmu = (const float*)d_in[20];
  const float* bmu = (const float*)d_in[21];
  const float* Wsig = (const float*)d_in[22];
  const float* bsig = (const float*)d_in[23];
  const float* eps = (const float*)d_in[24];
  float* z = (float*)d_out;

  const int M = 8192, D = 1024;
  char* ws = (char*)d_ws;
  size_t off = 0;
  auto alloc = [&](size_t b) {
    char* p = ws + off;
    off += (b + 255) & ~(size_t)255;
    return p;
  };
  bf16* wqkvT = (bf16*)alloc((size_t)3072 * 1024 * 2);  // [wq^T; wk^T; wv^T]
  bf16* woT = (bf16*)alloc((size_t)1024 * 1024 * 2);
  bf16* w1T = (bf16*)alloc((size_t)1024 * 1024 * 2);
  bf16* w2T = (bf16*)alloc((size_t)1024 * 1024 * 2);
  bf16* wmsT = (bf16*)alloc((size_t)256 * 1024 * 2);    // [Wmu^T ; Wsig^T]
  bf16* hb = (bf16*)alloc((size_t)M * D * 2);           // h1 (resid for Wo)
  bf16* Qb = (bf16*)alloc((size_t)M * D * 2);
  bf16* Kb = (bf16*)alloc((size_t)M * D * 2);
  bf16* Vb = (bf16*)alloc((size_t)M * D * 2);
  bf16* VtG = (bf16*)alloc((size_t)M * D * 2);
  bf16* Cb = (bf16*)alloc((size_t)M * D * 2);           // ctx
  bf16* h2b = (bf16*)alloc((size_t)M * D * 2);
  bf16* h3b = (bf16*)alloc((size_t)M * D * 2);
  bf16* hidb = (bf16*)alloc((size_t)M * D * 2);
  bf16* h4b = (bf16*)alloc((size_t)M * D * 2);
  bf16* h5b = (bf16*)alloc((size_t)M * D * 2);
  float* musg = (float*)alloc((size_t)M * 256 * 4);     // [8192,256] f32

  dim3 b256(256);
  TP8 tp;
  tp.src[0] = Wq;   tp.dst[0] = wqkvT;                        tp.ncol[0] = 1024;
  tp.src[1] = Wk;   tp.dst[1] = wqkvT + (size_t)1024 * 1024;  tp.ncol[1] = 1024;
  tp.src[2] = Wv;   tp.dst[2] = wqkvT + (size_t)2048 * 1024;  tp.ncol[2] = 1024;
  tp.src[3] = Wo;   tp.dst[3] = woT;                          tp.ncol[3] = 1024;
  tp.src[4] = W1;   tp.dst[4] = w1T;                          tp.ncol[4] = 1024;
  tp.src[5] = W2;   tp.dst[5] = w2T;                          tp.ncol[5] = 1024;
  tp.src[6] = Wmu;  tp.dst[6] = wmsT;                         tp.ncol[6] = 128;
  tp.src[7] = Wsig; tp.dst[7] = wmsT + (size_t)128 * 1024;    tp.ncol[7] = 128;
  transpose8_kernel<<<dim3(16, 16, 8), b256, 0, stream>>>(tp);

  embed_ln_kernel<<<8192, b256, 0, stream>>>(x, emb, g1, be1, hb);  // h1

  // fused QKV: N=3072, outputs routed to Qb/Kb/Vb (BK=32: keep 3 blocks/CU)
  gemm_kernel<6, 32><<<dim3(64, 24), b256, 0, stream>>>(hb, wqkvT, bq, bkb, bv,
                                                        Qb, Kb, Vb, nullptr, nullptr,
                                                        M, 3072, D);
  vtrans_kernel<<<dim3(256, 8), b256, 0, stream>>>(Vb, VtG);
  attn_kernel<<<dim3(256, 4), b256, 0, stream>>>(Qb, Kb, VtG, Cb);

  // grid-capped (2 blocks/CU) GEMMs: BK=64 halves barrier count
  gemm_kernel<1, 64><<<dim3(64, 8), b256, 0, stream>>>(Cb, woT, bo, nullptr, nullptr,
                                                       h2b, nullptr, nullptr, nullptr, hb,
                                                       M, D, D);
  ln_kernel<<<8192, b256, 0, stream>>>(h2b, g2, be2, h3b);
  gemm_kernel<2, 64><<<dim3(64, 8), b256, 0, stream>>>(h3b, w1T, bf1, nullptr, nullptr,
                                                       hidb, nullptr, nullptr, nullptr, nullptr,
                                                       M, D, D);
  gemm_kernel<3, 64><<<dim3(64, 8), b256, 0, stream>>>(hidb, w2T, bf2, nullptr, nullptr,
                                                       h4b, nullptr, nullptr, nullptr, nullptr,
                                                       M, D, D);
  ln_kernel<<<8192, b256, 0, stream>>>(h4b, g3, be3, h5b);
  gemm_kernel<5, 64><<<dim3(64, 2), b256, 0, stream>>>(h5b, wmsT, bmu, bsig, nullptr,
                                                       nullptr, nullptr, nullptr, musg, nullptr,
                                                       M, 256, D);
  final_kernel<<<1024, b256, 0, stream>>>(musg, eps, z);
}

// Round 5
// 432.600 us; speedup vs baseline: 1.3620x; 1.0034x over previous
//
#include <hip/hip_runtime.h>
#include <cstdint>

// FirstEncoder: B=16 S=512 D=1024 H=16 L=128 V=32000, DH=64.
// Faithful: raw-reshape head split (head (b,h) = contiguous [512,64] block of
// the flat [8192,1024] buffer), score scale 1/32 (DH/2), FFN residual f+f=2f.

typedef __bf16 bf16;
typedef __bf16 bf16x8 __attribute__((ext_vector_type(8)));
typedef __bf16 bf16x4 __attribute__((ext_vector_type(4)));
typedef float f32x4 __attribute__((ext_vector_type(4)));

#define MFMA16(a, b, c) __builtin_amdgcn_mfma_f32_16x16x32_bf16((a), (b), (c), 0, 0, 0)

#if __has_builtin(__builtin_amdgcn_exp2f)
#define EXP2F(x) __builtin_amdgcn_exp2f(x)
#else
#define EXP2F(x) exp2f(x)
#endif

// async 16B global->LDS (lane i lands at wave-uniform base + i*16)
__device__ __forceinline__ void async16(const bf16* g, bf16* l) {
  __builtin_amdgcn_global_load_lds(
      (const __attribute__((address_space(1))) unsigned int*)g,
      (__attribute__((address_space(3))) unsigned int*)l, 16, 0, 0);
}

// ---------------------------------------------------------------------------
// 8x fused weight transpose + f32->bf16. All have K=1024 rows; N = 1024 for
// the six D x D weights, 128 for Wmu/Wsig. Wt[n*1024 + k] = W[k*N + n].
struct TP8 {
  const float* src[8];
  bf16* dst[8];
  int ncol[8];
};
__global__ __launch_bounds__(256) void transpose8_kernel(TP8 p) {
  const int z = blockIdx.z;
  const int N = p.ncol[z];
  const int tk = blockIdx.x * 64, tn = blockIdx.y * 64;
  if (tn >= N) return;
  const float* __restrict__ W = p.src[z];
  bf16* __restrict__ Wt = p.dst[z];
  __shared__ float tile[64][65];
  const int a = threadIdx.x >> 6, b = threadIdx.x & 63;
#pragma unroll
  for (int i = 0; i < 16; ++i) {
    int k = a + i * 4;
    tile[k][b] = W[(size_t)(tk + k) * N + tn + b];
  }
  __syncthreads();
#pragma unroll
  for (int i = 0; i < 16; ++i) {
    int n = a + i * 4;
    Wt[(size_t)(tn + n) * 1024 + tk + b] = (bf16)tile[b][n];
  }
}

// ---------------------------------------------------------------------------
// Fused embed (*32 + posenc) + LayerNorm1 -> bf16 h1.
// Wave-per-row: 4 rows/block, 16 elems/lane, pure shuffle reduce (no barrier).
__global__ __launch_bounds__(256) void embed_ln_kernel(const int* __restrict__ x,
                                                       const float* __restrict__ emb,
                                                       const float* __restrict__ g,
                                                       const float* __restrict__ be,
                                                       bf16* __restrict__ obf) {
  const int w = threadIdx.x >> 6, lane = threadIdx.x & 63;
  const int row = blockIdx.x * 4 + w;
  const int s = row & 511;
  const int t = x[row];
  const int c0 = lane * 16;
  const float* er = emb + (size_t)t * 1024 + c0;
  float o[16];
#pragma unroll
  for (int i = 0; i < 4; ++i) {
    const float4 e = *(const float4*)(er + i * 4);
    o[i * 4 + 0] = e.x; o[i * 4 + 1] = e.y; o[i * 4 + 2] = e.z; o[i * 4 + 3] = e.w;
  }
#pragma unroll
  for (int p = 0; p < 8; ++p) {
    const int cc = c0 + 2 * p;
    const float freq = __expf((float)cc * (-9.210340371976184f / 1024.0f));
    const float ang = (float)s * freq;
    o[2 * p] = o[2 * p] * 32.0f + __sinf(ang);
    o[2 * p + 1] = o[2 * p + 1] * 32.0f + __cosf(ang);
  }
  float sm = 0.f, q = 0.f;
#pragma unroll
  for (int j = 0; j < 16; ++j) { sm += o[j]; q += o[j] * o[j]; }
#pragma unroll
  for (int off = 1; off < 64; off <<= 1) {
    sm += __shfl_xor(sm, off);
    q += __shfl_xor(q, off);
  }
  const float mean = sm * (1.0f / 1024.0f);
  const float var = q * (1.0f / 1024.0f) - mean * mean;
  const float rstd = rsqrtf(var + 1e-5f);
  bf16 ob[16];
#pragma unroll
  for (int i = 0; i < 4; ++i) {
    const float4 gv = *(const float4*)(g + c0 + i * 4);
    const float4 bv = *(const float4*)(be + c0 + i * 4);
    const float gvv[4] = {gv.x, gv.y, gv.z, gv.w};
    const float bvv[4] = {bv.x, bv.y, bv.z, bv.w};
#pragma unroll
    for (int j = 0; j < 4; ++j)
      ob[i * 4 + j] = (bf16)((o[i * 4 + j] - mean) * rstd * gvv[j] + bvv[j]);
  }
  bf16* dst = obf + (size_t)row * 1024 + c0;
  *(uint4*)dst = *(const uint4*)&ob[0];
  *(uint4*)(dst + 8) = *(const uint4*)&ob[8];
}

// ---------------------------------------------------------------------------
// LayerNorm over D=1024, bf16 in -> bf16 out. Wave-per-row, no barrier.
__global__ __launch_bounds__(256) void ln_kernel(const bf16* __restrict__ in,
                                                 const float* __restrict__ g,
                                                 const float* __restrict__ be,
                                                 bf16* __restrict__ obf) {
  const int w = threadIdx.x >> 6, lane = threadIdx.x & 63;
  const int row = blockIdx.x * 4 + w;
  const int c0 = lane * 16;
  const bf16* src = in + (size_t)row * 1024 + c0;
  const bf16x8 v0 = *(const bf16x8*)src;
  const bf16x8 v1 = *(const bf16x8*)(src + 8);
  float v[16];
#pragma unroll
  for (int j = 0; j < 8; ++j) { v[j] = (float)v0[j]; v[8 + j] = (float)v1[j]; }
  float s = 0.f, q = 0.f;
#pragma unroll
  for (int j = 0; j < 16; ++j) { s += v[j]; q += v[j] * v[j]; }
#pragma unroll
  for (int off = 1; off < 64; off <<= 1) {
    s += __shfl_xor(s, off);
    q += __shfl_xor(q, off);
  }
  const float mean = s * (1.0f / 1024.0f);
  const float var = q * (1.0f / 1024.0f) - mean * mean;
  const float rstd = rsqrtf(var + 1e-5f);
  bf16 ob[16];
#pragma unroll
  for (int i = 0; i < 4; ++i) {
    const float4 gv = *(const float4*)(g + c0 + i * 4);
    const float4 bv = *(const float4*)(be + c0 + i * 4);
    const float gvv[4] = {gv.x, gv.y, gv.z, gv.w};
    const float bvv[4] = {bv.x, bv.y, bv.z, bv.w};
#pragma unroll
    for (int j = 0; j < 4; ++j)
      ob[i * 4 + j] = (bf16)((v[i * 4 + j] - mean) * rstd * gvv[j] + bvv[j]);
  }
  bf16* dst = obf + (size_t)row * 1024 + c0;
  *(uint4*)dst = *(const uint4*)&ob[0];
  *(uint4*)(dst + 8) = *(const uint4*)&ob[8];
}

// ---------------------------------------------------------------------------
// GEMM: C[M,N] = A[M,K](bf16) @ Bt[N,K]^T(bf16) + bias.
// Single-barrier double-buffered K-loop, global_load_lds width-16, XOR swizzle.
// BK = 32 (16 KB/buf, 3 blocks/CU for big grids) or 64 (32 KB/buf — used where
// the grid caps occupancy at 2 blocks/CU anyway; halves barrier count).
// MODE 1: bf16 out = acc + b0 + resid(bf16)         (Wo)
// MODE 2: bf16 out = leaky_relu(acc + b0)           (W1)
// MODE 3: bf16 out = 2*(acc + b0)                   (W2, f+f)
// MODE 6: bf16 out routed to o0/o1/o2 by n-part     (fused QKV, N=3072)
template <int MODE, int BK>
__global__ __launch_bounds__(256) void gemm_kernel(
    const bf16* __restrict__ A, const bf16* __restrict__ Bt,
    const float* __restrict__ b0f, const float* __restrict__ b1f,
    const float* __restrict__ b2f,
    bf16* __restrict__ o0, bf16* __restrict__ o1, bf16* __restrict__ o2,
    const bf16* __restrict__ residb,
    int M, int N, int K) {
  __shared__ __attribute__((aligned(16))) bf16 Asm[2][128 * BK];
  __shared__ __attribute__((aligned(16))) bf16 Bsm[2][128 * BK];
  constexpr int KH = BK / 32;            // k-halves per tile iter
  constexpr int SPT = (128 * BK / 8) / 256;  // 16B slots per thread per matrix
  const int tid = threadIdx.x;
  const int wv = tid >> 6, lane = tid & 63;
  const int quad = lane >> 4, l15 = lane & 15;
  const int m0 = blockIdx.x * 128, n0 = blockIdx.y * 128;
  const int wm = wv & 1, wn = wv >> 1;

  f32x4 acc[4][4];
#pragma unroll
  for (int i = 0; i < 4; ++i)
#pragma unroll
    for (int j = 0; j < 4; ++j) acc[i][j] = {0.f, 0.f, 0.f, 0.f};

  const bf16* Aglb[SPT];
  const bf16* Bglb[SPT];
  int soff[SPT];
#pragma unroll
  for (int i = 0; i < SPT; ++i) {
    const int s = tid + i * 256;
    int row, col;
    if constexpr (BK == 32) {
      row = s >> 2;
      col = (s & 3) ^ ((row >> 1) & 3);
    } else {
      row = s >> 3;
      col = (s & 7) ^ (row & 7);
    }
    Aglb[i] = A + (size_t)(m0 + row) * K + col * 8;
    Bglb[i] = Bt + (size_t)(n0 + row) * K + col * 8;
    soff[i] = s * 8;
  }

#pragma unroll
  for (int i = 0; i < SPT; ++i) async16(Aglb[i], &Asm[0][soff[i]]);
#pragma unroll
  for (int i = 0; i < SPT; ++i) async16(Bglb[i], &Bsm[0][soff[i]]);
  __syncthreads();

  const int nk = K / BK;
  for (int k = 0; k < nk; ++k) {
    const int cur = k & 1, nxt = cur ^ 1;
    bf16x8 af[4][KH], bfr[4][KH];
#pragma unroll
    for (int mi = 0; mi < 4; ++mi) {
      const int row = wm * 64 + mi * 16 + l15;
#pragma unroll
      for (int h = 0; h < KH; ++h) {
        int pos;
        if constexpr (BK == 32) pos = quad ^ ((row >> 1) & 3);
        else pos = (h * 4 + quad) ^ (row & 7);
        af[mi][h] = *(const bf16x8*)(&Asm[cur][(row * (BK / 8) + pos) * 8]);
      }
    }
#pragma unroll
    for (int ni = 0; ni < 4; ++ni) {
      const int row = wn * 64 + ni * 16 + l15;
#pragma unroll
      for (int h = 0; h < KH; ++h) {
        int pos;
        if constexpr (BK == 32) pos = quad ^ ((row >> 1) & 3);
        else pos = (h * 4 + quad) ^ (row & 7);
        bfr[ni][h] = *(const bf16x8*)(&Bsm[cur][(row * (BK / 8) + pos) * 8]);
      }
    }
    if (k + 1 < nk) {
      const int ko = (k + 1) * BK;
#pragma unroll
      for (int i = 0; i < SPT; ++i) async16(Aglb[i] + ko, &Asm[nxt][soff[i]]);
#pragma unroll
      for (int i = 0; i < SPT; ++i) async16(Bglb[i] + ko, &Bsm[nxt][soff[i]]);
    }
#pragma unroll
    for (int h = 0; h < KH; ++h)
#pragma unroll
      for (int mi = 0; mi < 4; ++mi)
#pragma unroll
        for (int ni = 0; ni < 4; ++ni)
          acc[mi][ni] = MFMA16(af[mi][h], bfr[ni][h], acc[mi][ni]);
    __syncthreads();
  }

  const int part = (MODE == 6) ? (blockIdx.y >> 3) : 0;
  bf16* ob = o0;
  const float* bp = b0f;
  if constexpr (MODE == 6) {
    ob = (part == 0) ? o0 : (part == 1 ? o1 : o2);
    bp = (part == 0) ? b0f : (part == 1 ? b1f : b2f);
  }
#pragma unroll
  for (int ni = 0; ni < 4; ++ni) {
    const int col = n0 + wn * 64 + ni * 16 + l15;
    const int cl = (MODE == 6) ? (col - part * 1024) : col;
    const float bv = bp[cl];
#pragma unroll
    for (int mi = 0; mi < 4; ++mi) {
#pragma unroll
      for (int r = 0; r < 4; ++r) {
        const int row = m0 + wm * 64 + mi * 16 + quad * 4 + r;
        float v = acc[mi][ni][r] + bv;
        if constexpr (MODE == 1) {
          const size_t idx = (size_t)row * N + col;
          o0[idx] = (bf16)(v + (float)residb[idx]);
        } else if constexpr (MODE == 2) {
          o0[(size_t)row * N + col] = (bf16)(v > 0.f ? v : 0.01f * v);
        } else if constexpr (MODE == 3) {
          o0[(size_t)row * N + col] = (bf16)(2.0f * v);
        } else {  // MODE 6
          ob[(size_t)row * 1024 + cl] = (bf16)v;
        }
      }
    }
  }
}

// ---------------------------------------------------------------------------
// mu|sig GEMM: C[8192,256] f32 = A[8192,1024] @ wmsT^T + bias(mu|sig).
// 64x128 tile, grid (128,2) = 256 blocks (1/CU vs 0.5/CU for 128-tile).
// 4 waves: wave (wm=wv&1, wn=wv>>1) owns 32 rows x 64 cols -> acc[2][4].
__global__ __launch_bounds__(256) void gemm_musig(const bf16* __restrict__ A,
                                                  const bf16* __restrict__ Bt,
                                                  const float* __restrict__ bmu,
                                                  const float* __restrict__ bsig,
                                                  float* __restrict__ of) {
  constexpr int BK = 64;
  __shared__ __attribute__((aligned(16))) bf16 Asm[2][64 * BK];
  __shared__ __attribute__((aligned(16))) bf16 Bsm[2][128 * BK];
  const int tid = threadIdx.x;
  const int wv = tid >> 6, lane = tid & 63;
  const int quad = lane >> 4, l15 = lane & 15;
  const int m0 = blockIdx.x * 64, n0 = blockIdx.y * 128;
  const int wm = wv & 1, wn = wv >> 1;

  f32x4 acc[2][4];
#pragma unroll
  for (int i = 0; i < 2; ++i)
#pragma unroll
    for (int j = 0; j < 4; ++j) acc[i][j] = {0.f, 0.f, 0.f, 0.f};

  // A: 64 rows x 8 chunks = 512 slots (2/thread); B: 128 x 8 = 1024 (4/thread)
  const bf16* Aglb[2];
  int asoff[2];
#pragma unroll
  for (int i = 0; i < 2; ++i) {
    const int s = tid + i * 256;
    const int row = s >> 3, col = (s & 7) ^ (row & 7);
    Aglb[i] = A + (size_t)(m0 + row) * 1024 + col * 8;
    asoff[i] = s * 8;
  }
  const bf16* Bglb[4];
  int bsoff[4];
#pragma unroll
  for (int i = 0; i < 4; ++i) {
    const int s = tid + i * 256;
    const int row = s >> 3, col = (s & 7) ^ (row & 7);
    Bglb[i] = Bt + (size_t)(n0 + row) * 1024 + col * 8;
    bsoff[i] = s * 8;
  }

#pragma unroll
  for (int i = 0; i < 2; ++i) async16(Aglb[i], &Asm[0][asoff[i]]);
#pragma unroll
  for (int i = 0; i < 4; ++i) async16(Bglb[i], &Bsm[0][bsoff[i]]);
  __syncthreads();

  for (int k = 0; k < 16; ++k) {
    const int cur = k & 1, nxt = cur ^ 1;
    bf16x8 af[2][2], bfr[4][2];
#pragma unroll
    for (int mi = 0; mi < 2; ++mi) {
      const int row = wm * 32 + mi * 16 + l15;
#pragma unroll
      for (int h = 0; h < 2; ++h) {
        const int pos = (h * 4 + quad) ^ (row & 7);
        af[mi][h] = *(const bf16x8*)(&Asm[cur][(row * 8 + pos) * 8]);
      }
    }
#pragma unroll
    for (int ni = 0; ni < 4; ++ni) {
      const int row = wn * 64 + ni * 16 + l15;
#pragma unroll
      for (int h = 0; h < 2; ++h) {
        const int pos = (h * 4 + quad) ^ (row & 7);
        bfr[ni][h] = *(const bf16x8*)(&Bsm[cur][(row * 8 + pos) * 8]);
      }
    }
    if (k + 1 < 16) {
      const int ko = (k + 1) * BK;
#pragma unroll
      for (int i = 0; i < 2; ++i) async16(Aglb[i] + ko, &Asm[nxt][asoff[i]]);
#pragma unroll
      for (int i = 0; i < 4; ++i) async16(Bglb[i] + ko, &Bsm[nxt][bsoff[i]]);
    }
#pragma unroll
    for (int h = 0; h < 2; ++h)
#pragma unroll
      for (int mi = 0; mi < 2; ++mi)
#pragma unroll
        for (int ni = 0; ni < 4; ++ni)
          acc[mi][ni] = MFMA16(af[mi][h], bfr[ni][h], acc[mi][ni]);
    __syncthreads();
  }

#pragma unroll
  for (int ni = 0; ni < 4; ++ni) {
    const int col = n0 + wn * 64 + ni * 16 + l15;
    const float bv = (col < 128) ? bmu[col] : bsig[col - 128];
#pragma unroll
    for (int mi = 0; mi < 2; ++mi) {
#pragma unroll
      for (int r = 0; r < 4; ++r) {
        const int row = m0 + wm * 32 + mi * 16 + quad * 4 + r;
        of[(size_t)row * 256 + col] = acc[mi][ni][r] + bv;
      }
    }
  }
}

// ---------------------------------------------------------------------------
// V transpose per head: Vb flat [256 bh][512 kv][64 d] -> VtG [256 bh][64 d][512 kv]
__global__ __launch_bounds__(256) void vtrans_kernel(const bf16* __restrict__ Vb,
                                                     bf16* __restrict__ VtG) {
  __shared__ float t[64][65];
  const int bh = blockIdx.x, kt = blockIdx.y;
  const int tid = threadIdx.x;
  const bf16* src = Vb + (size_t)bh * 32768 + (size_t)kt * 4096;
#pragma unroll
  for (int i = 0; i < 2; ++i) {
    int s = i * 256 + tid;
    int r = s >> 3, c = (s & 7) * 8;
    bf16x8 v = *(const bf16x8*)(src + (size_t)s * 8);
#pragma unroll
    for (int j = 0; j < 8; ++j) t[r][c + j] = (float)v[j];
  }
  __syncthreads();
  bf16* dst = VtG + (size_t)bh * 32768 + kt * 64;
#pragma unroll
  for (int i = 0; i < 2; ++i) {
    int s = i * 256 + tid;
    int d = s >> 3, kc = (s & 7) * 8;
    bf16 tmp[8];
#pragma unroll
    for (int j = 0; j < 8; ++j) tmp[j] = (bf16)t[kc + j][d];
    *(uint4*)(dst + (size_t)d * 512 + kc) = *(const uint4*)tmp;
  }
}

// ---------------------------------------------------------------------------
// Flash-style attention. grid (256 bh, 4 qblk), 256 threads (4 waves).
// No-max softmax (|score/32| small): p = exp2(score * log2e/32) via Q prescale.
__global__ __launch_bounds__(256) void attn_kernel(const bf16* __restrict__ Qg,
                                                   const bf16* __restrict__ Kg,
                                                   const bf16* __restrict__ Vt,
                                                   bf16* __restrict__ ctx) {
  __shared__ __attribute__((aligned(16))) bf16 Ksm[128 * 64];
  __shared__ __attribute__((aligned(16))) bf16 Vsm[64 * 128];
  __shared__ __attribute__((aligned(16))) bf16 Psm[4][16 * 128];
  const int tid = threadIdx.x;
  const int w = tid >> 6, lane = tid & 63;
  const int quad = lane >> 4, l15 = lane & 15;
  const int bh = blockIdx.x;
  const size_t base = (size_t)bh * 32768;
  const bf16* Vth = Vt + base;
  const int qbase = blockIdx.y * 128 + w * 32;
  const f32x4 fz = {0.f, 0.f, 0.f, 0.f};

  bf16x8 a[2][2];
#pragma unroll
  for (int qt = 0; qt < 2; ++qt)
#pragma unroll
    for (int hf = 0; hf < 2; ++hf) {
      bf16x8 tq = *(const bf16x8*)(Qg + base +
                   (size_t)(qbase + qt * 16 + l15) * 64 + hf * 32 + quad * 8);
#pragma unroll
      for (int e = 0; e < 8; ++e) tq[e] = (bf16)((float)tq[e] * 0.045111758f);
      a[qt][hf] = tq;
    }

  f32x4 o[2][4];
  float l_i[2][4];
#pragma unroll
  for (int qt = 0; qt < 2; ++qt)
#pragma unroll
    for (int i = 0; i < 4; ++i) { o[qt][i] = fz; l_i[qt][i] = 0.f; }

  for (int kv0 = 0; kv0 < 512; kv0 += 128) {
#pragma unroll
    for (int i = 0; i < 4; ++i) {
      int s = i * 256 + tid;
      int r = s >> 3, c = (s & 7) ^ (r & 7);
      async16(Kg + base + (size_t)(kv0 + r) * 64 + c * 8, &Ksm[s * 8]);
    }
#pragma unroll
    for (int i = 0; i < 4; ++i) {
      int s = i * 256 + tid;
      int d = s >> 4, cs = s & 15;
      int c = (cs & 8) | ((cs & 7) ^ (d & 7));
      async16(Vth + (size_t)d * 512 + kv0 + c * 8, &Vsm[s * 8]);
    }
    __syncthreads();

    f32x4 sc[2][8];
#pragma unroll
    for (int j = 0; j < 8; ++j) {
      const int n = j * 16 + l15;
      const bf16x8 k0 = *(const bf16x8*)(&Ksm[(n * 8 + (quad ^ (n & 7))) * 8]);
      const bf16x8 k1 = *(const bf16x8*)(&Ksm[(n * 8 + ((4 + quad) ^ (n & 7))) * 8]);
      sc[0][j] = MFMA16(a[0][0], k0, fz);
      sc[0][j] = MFMA16(a[0][1], k1, sc[0][j]);
      sc[1][j] = MFMA16(a[1][0], k0, fz);
      sc[1][j] = MFMA16(a[1][1], k1, sc[1][j]);
    }

    bf16* ps = &Psm[w][0];
#pragma unroll
    for (int qt = 0; qt < 2; ++qt) {
#pragma unroll
      for (int r = 0; r < 4; ++r) {
        const int prow = quad * 4 + r;
        float sum = 0.f;
#pragma unroll
        for (int j = 0; j < 8; ++j) {
          const float p = EXP2F(sc[qt][j][r]);
          sum += p;
          const int col = j * 16 + l15;
          const int cc = col >> 3;
          const int ccs = (cc & 8) | ((cc & 7) ^ (prow & 7));
          ps[prow * 128 + ccs * 8 + (col & 7)] = (bf16)p;
        }
        l_i[qt][r] += sum;
      }
#pragma unroll
      for (int c32 = 0; c32 < 4; ++c32) {
        const int pc = c32 * 4 + quad;
        const int pcs = (pc & 8) | ((pc & 7) ^ (l15 & 7));
        const bf16x8 pf = *(const bf16x8*)(ps + l15 * 128 + pcs * 8);
#pragma unroll
        for (int ni = 0; ni < 4; ++ni) {
          const int d = ni * 16 + l15;
          const int vcs = (pc & 8) | ((pc & 7) ^ (d & 7));
          const bf16x8 vf = *(const bf16x8*)(&Vsm[(d * 16 + vcs) * 8]);
          o[qt][ni] = MFMA16(pf, vf, o[qt][ni]);
        }
      }
    }
    __syncthreads();
  }

#pragma unroll
  for (int qt = 0; qt < 2; ++qt) {
#pragma unroll
    for (int r = 0; r < 4; ++r) {
      float l = l_i[qt][r];
      l += __shfl_xor(l, 1);
      l += __shfl_xor(l, 2);
      l += __shfl_xor(l, 4);
      l += __shfl_xor(l, 8);
      const float inv = 1.0f / l;
#pragma unroll
      for (int ni = 0; ni < 4; ++ni)
        ctx[base + (size_t)(qbase + qt * 16 + quad * 4 + r) * 64 + ni * 16 + l15]
            = (bf16)(o[qt][ni][r] * inv);
    }
  }
}

// ---------------------------------------------------------------------------
// z = mu + exp(sig_raw) * eps from fused [8192,256] mu|sig buffer.
__global__ __launch_bounds__(256) void final_kernel(const float* __restrict__ musg,
                                                    const float* __restrict__ eps,
                                                    float* __restrict__ z) {
  const int i = blockIdx.x * 256 + threadIdx.x;
  const int row = i >> 5;
  const int c = (i & 31) * 4;
  const float4 m = *(const float4*)(musg + (size_t)row * 256 + c);
  const float4 s = *(const float4*)(musg + (size_t)row * 256 + 128 + c);
  const float4 e = *(const float4*)(eps + (size_t)row * 128 + c);
  float4 r;
  r.x = m.x + __expf(s.x) * e.x;
  r.y = m.y + __expf(s.y) * e.y;
  r.z = m.z + __expf(s.z) * e.z;
  r.w = m.w + __expf(s.w) * e.w;
  *(float4*)(z + (size_t)row * 128 + c) = r;
}

// ---------------------------------------------------------------------------
extern "C" void kernel_launch(void* const* d_in, const int* in_sizes, int n_in,
                              void* d_out, int out_size, void* d_ws, size_t ws_size,
                              hipStream_t stream) {
  (void)in_sizes; (void)n_in; (void)out_size; (void)ws_size;
  const int* x = (const int*)d_in[0];
  const float* emb = (const float*)d_in[1];
  const float* Wq = (const float*)d_in[2];
  const float* bq = (const float*)d_in[3];
  const float* Wk = (const float*)d_in[4];
  const float* bkb = (const float*)d_in[5];
  const float* Wv = (const float*)d_in[6];
  const float* bv = (const float*)d_in[7];
  const float* Wo = (const float*)d_in[8];
  const float* bo = (const float*)d_in[9];
  const float* g1 = (const float*)d_in[10];
  const float* be1 = (const float*)d_in[11];
  const float* W1 = (const float*)d_in[12];
  const float* bf1 = (const float*)d_in[13];
  const float* W2 = (const float*)d_in[14];
  const float* bf2 = (const float*)d_in[15];
  const float* g2 = (const float*)d_in[16];
  const float* be2 = (const float*)d_in[17];
  const float* g3 = (const float*)d_in[18];
  const float* be3 = (const float*)d_in[19];
  const float* Wmu = (const float*)d_in[20];
  const float* bmu = (const float*)d_in[21];
  const float* Wsig = (const float*)d_in[22];
  const float* bsig = (const float*)d_in[23];
  const float* eps = (const float*)d_in[24];
  float* z = (float*)d_out;

  const int M = 8192, D = 1024;
  char* ws = (char*)d_ws;
  size_t off = 0;
  auto alloc = [&](size_t b) {
    char* p = ws + off;
    off += (b + 255) & ~(size_t)255;
    return p;
  };
  bf16* wqkvT = (bf16*)alloc((size_t)3072 * 1024 * 2);  // [wq^T; wk^T; wv^T]
  bf16* woT = (bf16*)alloc((size_t)1024 * 1024 * 2);
  bf16* w1T = (bf16*)alloc((size_t)1024 * 1024 * 2);
  bf16* w2T = (bf16*)alloc((size_t)1024 * 1024 * 2);
  bf16* wmsT = (bf16*)alloc((size_t)256 * 1024 * 2);    // [Wmu^T ; Wsig^T]
  bf16* hb = (bf16*)alloc((size_t)M * D * 2);           // h1 (resid for Wo)
  bf16* Qb = (bf16*)alloc((size_t)M * D * 2);
  bf16* Kb = (bf16*)alloc((size_t)M * D * 2);
  bf16* Vb = (bf16*)alloc((size_t)M * D * 2);
  bf16* VtG = (bf16*)alloc((size_t)M * D * 2);
  bf16* Cb = (bf16*)alloc((size_t)M * D * 2);           // ctx
  bf16* h2b = (bf16*)alloc((size_t)M * D * 2);
  bf16* h3b = (bf16*)alloc((size_t)M * D * 2);
  bf16* hidb = (bf16*)alloc((size_t)M * D * 2);
  bf16* h4b = (bf16*)alloc((size_t)M * D * 2);
  bf16* h5b = (bf16*)alloc((size_t)M * D * 2);
  float* musg = (float*)alloc((size_t)M * 256 * 4);     // [8192,256] f32

  dim3 b256(256);
  TP8 tp;
  tp.src[0] = Wq;   tp.dst[0] = wqkvT;                        tp.ncol[0] = 1024;
  tp.src[1] = Wk;   tp.dst[1] = wqkvT + (size_t)1024 * 1024;  tp.ncol[1] = 1024;
  tp.src[2] = Wv;   tp.dst[2] = wqkvT + (size_t)2048 * 1024;  tp.ncol[2] = 1024;
  tp.src[3] = Wo;   tp.dst[3] = woT;                          tp.ncol[3] = 1024;
  tp.src[4] = W1;   tp.dst[4] = w1T;                          tp.ncol[4] = 1024;
  tp.src[5] = W2;   tp.dst[5] = w2T;                          tp.ncol[5] = 1024;
  tp.src[6] = Wmu;  tp.dst[6] = wmsT;                         tp.ncol[6] = 128;
  tp.src[7] = Wsig; tp.dst[7] = wmsT + (size_t)128 * 1024;    tp.ncol[7] = 128;
  transpose8_kernel<<<dim3(16, 16, 8), b256, 0, stream>>>(tp);

  embed_ln_kernel<<<2048, b256, 0, stream>>>(x, emb, g1, be1, hb);  // h1

  // fused QKV: N=3072, outputs routed to Qb/Kb/Vb (BK=32: keep 3 blocks/CU)
  gemm_kernel<6, 32><<<dim3(64, 24), b256, 0, stream>>>(hb, wqkvT, bq, bkb, bv,
                                                        Qb, Kb, Vb, nullptr,
                                                        M, 3072, D);
  vtrans_kernel<<<dim3(256, 8), b256, 0, stream>>>(Vb, VtG);
  attn_kernel<<<dim3(256, 4), b256, 0, stream>>>(Qb, Kb, VtG, Cb);

  // grid-capped (2 blocks/CU) GEMMs: BK=64 halves barrier count
  gemm_kernel<1, 64><<<dim3(64, 8), b256, 0, stream>>>(Cb, woT, bo, nullptr, nullptr,
                                                       h2b, nullptr, nullptr, hb,
                                                       M, D, D);
  ln_kernel<<<2048, b256, 0, stream>>>(h2b, g2, be2, h3b);
  gemm_kernel<2, 64><<<dim3(64, 8), b256, 0, stream>>>(h3b, w1T, bf1, nullptr, nullptr,
                                                       hidb, nullptr, nullptr, nullptr,
                                                       M, D, D);
  gemm_kernel<3, 64><<<dim3(64, 8), b256, 0, stream>>>(hidb, w2T, bf2, nullptr, nullptr,
                                                       h4b, nullptr, nullptr, nullptr,
                                                       M, D, D);
  ln_kernel<<<2048, b256, 0, stream>>>(h4b, g3, be3, h5b);
  gemm_musig<<<dim3(128, 2), b256, 0, stream>>>(h5b, wmsT, bmu, bsig, musg);
  final_kernel<<<1024, b256, 0, stream>>>(musg, eps, z);
}